// Round 15
// baseline (416.333 us; speedup 1.0000x reference)
//
#include <hip/hip_runtime.h>
#include <hip/hip_bf16.h>
#include <cstdint>
#include <cstddef>

// Problem constants
static constexpr int N_TOK = 49152;     // B*M = 8192*6
// d_out offsets (floats), outputs concatenated in reference return order
static constexpr size_t OFF_TRAJ     = 0;          // [N,120]
static constexpr size_t OFF_SCORE    = 5898240;    // [N]
static constexpr size_t OFF_LOGITS   = 5947392;    // [N,5]
static constexpr size_t OFF_IDX      = 6193152;    // [N,2]  (ints stored as floats)
static constexpr size_t OFF_AUX      = 6291456;    // [1]
static constexpr size_t OFF_TRAJALL  = 6291457;    // [5,N,120]
static constexpr size_t OFF_SCOREALL = 35782657;   // [5,N]

typedef short s16x8 __attribute__((ext_vector_type(8)));
typedef float f32x4 __attribute__((ext_vector_type(4)));
typedef f32x4 f32x4u __attribute__((aligned(4)));   // reduced-alignment variant
typedef unsigned int u32;
typedef unsigned short u16;

// packed bf16 weight offsets (u16 elems): [6][H][K] per layer (experts 0-4, shared=5)
static constexpr u32 O_T1 = 0,      O_T2 = 196608, O_T3 = 589824;
static constexpr u32 O_S1 = 774144, O_S2 = 872448;
// packed fp32 offsets (floats)
static constexpr u32 OB_T1 = 0, OB_T2 = 1536, OB_T3 = 3072, OB_S1 = 3792, OB_S2 = 4560;
static constexpr u32 OW_S3 = 4944, OB_S3 = 5328;

// exact gelu (router path: logits feed exact-match topk)
__device__ __forceinline__ float gelu_exact(float x) {
    return 0.5f * x * (1.0f + erff(x * 0.70710678118654752440f));
}
// fast gelu: x*sigmoid(1.5957691*(x+0.044715x^3)); rcp instead of exact division
__device__ __forceinline__ float gelu_f(float x) {
    const float x2 = x * x;
    const float u  = x * fmaf(0.07135486172f, x2, 1.5957691216057308f);
    const float t  = __expf(-u);
    return x * __builtin_amdgcn_rcpf(1.0f + t);
}
__device__ __forceinline__ float bf2f(u16 u) {
    return __uint_as_float(((u32)u) << 16);
}
__device__ __forceinline__ u16 f2bf(float v) {
    return ((__hip_bfloat16_raw)__float2bfloat16(v)).x;
}
__device__ __forceinline__ void gload16(const u16* g, u16* l) {
    __builtin_amdgcn_global_load_lds(
        (const __attribute__((address_space(1))) u32*)g,
        (__attribute__((address_space(3))) u32*)l, 16, 0, 0);
}
#define MFMA16(a, b, c) __builtin_amdgcn_mfma_f32_16x16x32_bf16(a, b, c, 0, 0, 0)
#define SBAR() __builtin_amdgcn_sched_barrier(0)

// swizzled LDS fragment read: logical (row r, 16B-chunk c) at chunk slot c^(r&7)
__device__ __forceinline__ s16x8 lds_frag(const u16* buf, int RBu16, int r, int c) {
    return *(const s16x8*)&buf[r * RBu16 + ((c ^ (r & 7)) << 3)];
}
// swizzled 8B LDS store of 4 consecutive bf16 cols (colb % 4 == 0)
__device__ __forceinline__ void lds_store4(u16* buf, int RBu16, int r, int colb,
                                           float v0, float v1, float v2, float v3) {
    const int ch = (colb >> 3) ^ (r & 7);
    ushort4 st = { f2bf(v0), f2bf(v1), f2bf(v2), f2bf(v3) };
    *(ushort4*)&buf[r * RBu16 + ch * 8 + (colb & 7)] = st;
}

// ---------------------------------------------------------------------------
// Fully fused fp32 router: x -> h1 -> h2 -> logits -> softmax/top2/gates,
// all LDS-resident per 32-token block. Also emits xb (bf16 x) while x is in
// LDS (replaces convert_x). Weights staged in K-chunks. Register tile:
// 4 tokens x 4 cols per thread (FMA:LDS-read ~2.7:1 -> VALU-bound).
// LDS 80 KB -> 2 blocks/CU. fp32 exactness preserved (topk_idx requirement).
// ---------------------------------------------------------------------------
__global__ __launch_bounds__(512, 2)
void router_fused(const float* __restrict__ x, const float* __restrict__ rw1,
                  const float* __restrict__ rb1, const float* __restrict__ rw2,
                  const float* __restrict__ rb2, const float* __restrict__ rw3,
                  const float* __restrict__ rb3, u16* __restrict__ xb,
                  float* __restrict__ logits, float* __restrict__ oidx,
                  float* __restrict__ tp, int* __restrict__ ti,
                  float* __restrict__ part)
{
    __shared__ float bufA[32 * 128];   // 16 KB: x tile; later w2 chunks
    __shared__ float bufB[32 * 256];   // 32 KB: w1 chunks; later h2 [32][128]
    __shared__ float bufC[32 * 256];   // 32 KB: h1; later per-token probs

    const int tid  = threadIdx.x;
    const int row0 = blockIdx.x * 32;
    const int tg   = tid >> 6;          // 0..7: token group (4 tokens)
    const int cl   = tid & 63;          // col lane
    const int t0   = tg * 4;

    // ---- load x tile [32][128] fp32 (4096 floats, 2 float4/thread) ----
    {
        const float* src = x + (size_t)row0 * 128;
        #pragma unroll
        for (int i = 0; i < 2; ++i)
            *(float4*)&bufA[i * 2048 + tid * 4] = *(const float4*)&src[i * 2048 + tid * 4];
    }
    __syncthreads();

    // ---- emit xb bf16 (8 elems/thread, contiguous) ----
    {
        u16* dst = xb + (size_t)row0 * 128;
        const int base = tid * 8;
        ushort4 o0, o1;
        o0.x = f2bf(bufA[base + 0]); o0.y = f2bf(bufA[base + 1]);
        o0.z = f2bf(bufA[base + 2]); o0.w = f2bf(bufA[base + 3]);
        o1.x = f2bf(bufA[base + 4]); o1.y = f2bf(bufA[base + 5]);
        o1.z = f2bf(bufA[base + 6]); o1.w = f2bf(bufA[base + 7]);
        *(ushort4*)&dst[base]     = o0;
        *(ushort4*)&dst[base + 4] = o1;
    }

    // ---- L1: h1[32][256] = gelu(x @ rw1 + rb1), K=128 in 4 chunks ----
    float acc1[4][4] = {};
    for (int k0 = 0; k0 < 128; k0 += 32) {
        __syncthreads();   // previous chunk's compute reads done
        #pragma unroll
        for (int i = 0; i < 4; ++i)
            *(float4*)&bufB[i * 2048 + tid * 4] =
                *(const float4*)&rw1[(size_t)k0 * 256 + i * 2048 + tid * 4];
        __syncthreads();
        #pragma unroll
        for (int kk = 0; kk < 32; ++kk) {
            const float4 wv = *(const float4*)&bufB[kk * 256 + cl * 4];
            #pragma unroll
            for (int i = 0; i < 4; ++i) {
                const float xv = bufA[(t0 + i) * 128 + k0 + kk];
                acc1[i][0] = fmaf(xv, wv.x, acc1[i][0]);
                acc1[i][1] = fmaf(xv, wv.y, acc1[i][1]);
                acc1[i][2] = fmaf(xv, wv.z, acc1[i][2]);
                acc1[i][3] = fmaf(xv, wv.w, acc1[i][3]);
            }
        }
    }
    {
        const float4 b1 = *(const float4*)&rb1[cl * 4];
        #pragma unroll
        for (int i = 0; i < 4; ++i) {
            bufC[(t0 + i) * 256 + cl * 4 + 0] = gelu_exact(acc1[i][0] + b1.x);
            bufC[(t0 + i) * 256 + cl * 4 + 1] = gelu_exact(acc1[i][1] + b1.y);
            bufC[(t0 + i) * 256 + cl * 4 + 2] = gelu_exact(acc1[i][2] + b1.z);
            bufC[(t0 + i) * 256 + cl * 4 + 3] = gelu_exact(acc1[i][3] + b1.w);
        }
    }
    __syncthreads();   // h1 visible; L1's bufA reads done

    // ---- L2: h2[32][128] = gelu(h1 @ rw2 + rb2), K=256 in 8 chunks ----
    float acc2[4][2] = {};
    for (int k0 = 0; k0 < 256; k0 += 32) {
        __syncthreads();   // previous chunk's compute reads done
        #pragma unroll
        for (int i = 0; i < 2; ++i)
            *(float4*)&bufA[i * 2048 + tid * 4] =
                *(const float4*)&rw2[(size_t)k0 * 128 + i * 2048 + tid * 4];
        __syncthreads();
        #pragma unroll
        for (int kk = 0; kk < 32; ++kk) {
            const float2 wv = *(const float2*)&bufA[kk * 128 + cl * 2];
            #pragma unroll
            for (int i = 0; i < 4; ++i) {
                const float hv = bufC[(t0 + i) * 256 + k0 + kk];
                acc2[i][0] = fmaf(hv, wv.x, acc2[i][0]);
                acc2[i][1] = fmaf(hv, wv.y, acc2[i][1]);
            }
        }
    }
    {
        const float2 b2 = *(const float2*)&rb2[cl * 2];
        #pragma unroll
        for (int i = 0; i < 4; ++i) {
            bufB[(t0 + i) * 128 + cl * 2 + 0] = gelu_exact(acc2[i][0] + b2.x);
            bufB[(t0 + i) * 128 + cl * 2 + 1] = gelu_exact(acc2[i][1] + b2.y);
        }
    }
    __syncthreads();   // h2 ready; h1 reads done -> bufC reusable for probs

    // ---- L3 + softmax + top-2 (token = tid>>4, 16 lanes K-split) ----
    {
        const int tok = tid >> 4;
        const int ln  = tid & 15;
        float l5[5] = {0.f, 0.f, 0.f, 0.f, 0.f};
        #pragma unroll
        for (int kk = 0; kk < 8; ++kk) {
            const float hv = bufB[tok * 128 + ln * 8 + kk];
            #pragma unroll
            for (int e = 0; e < 5; ++e)
                l5[e] = fmaf(hv, rw3[(size_t)(ln * 8 + kk) * 5 + e], l5[e]);
        }
        #pragma unroll
        for (int off = 8; off > 0; off >>= 1)
            #pragma unroll
            for (int e = 0; e < 5; ++e)
                l5[e] += __shfl_xor(l5[e], off);

        if (ln == 0) {
            const int n = row0 + tok;
            float l[5];
            #pragma unroll
            for (int e = 0; e < 5; ++e) {
                l[e] = l5[e] + rb3[e];
                logits[(size_t)n * 5 + e] = l[e];
            }
            // full softmax (aux partials)
            float m = l[0];
            #pragma unroll
            for (int e = 1; e < 5; ++e) m = fmaxf(m, l[e]);
            float p[5], s = 0.f;
            #pragma unroll
            for (int e = 0; e < 5; ++e) { p[e] = expf(l[e] - m); s += p[e]; }
            const float inv = 1.0f / s;
            #pragma unroll
            for (int e = 0; e < 5; ++e) bufC[tok * 5 + e] = p[e] * inv;

            // top-2 (ties keep lower index, matching jax.lax.top_k)
            int i0 = 0; float v0 = l[0];
            #pragma unroll
            for (int e = 1; e < 5; ++e) if (l[e] > v0) { v0 = l[e]; i0 = e; }
            int i1 = -1; float v1 = -1e30f;
            #pragma unroll
            for (int e = 0; e < 5; ++e) if (e != i0 && l[e] > v1) { v1 = l[e]; i1 = e; }

            const float t  = expf(v1 - v0);
            const float q0 = 1.0f / (1.0f + t);
            const float q1 = t / (1.0f + t);

            oidx[(size_t)n * 2]     = (float)i0;
            oidx[(size_t)n * 2 + 1] = (float)i1;
            tp[n * 2] = q0; tp[n * 2 + 1] = q1;
            ti[n * 2] = i0; ti[n * 2 + 1] = i1;
        }
    }
    __syncthreads();
    if (tid < 5) {
        float s = 0.f;
        #pragma unroll 8
        for (int t = 0; t < 32; ++t) s += bufC[t * 5 + tid];
        part[blockIdx.x * 5 + tid] = s;
    }
}

__global__ __launch_bounds__(256)
void aux_kernel(const float* __restrict__ part, float* __restrict__ aux)
{
    __shared__ float avg[5];
    const int tid = threadIdx.x;
    if (tid < 5) {
        float s = 0.f;
        for (int b = 0; b < 1536; ++b) s += part[b * 5 + tid];
        avg[tid] = s / (float)N_TOK;
    }
    __syncthreads();
    if (tid == 0) {
        float ent = 0.f, l2 = 0.f;
        #pragma unroll
        for (int e = 0; e < 5; ++e) {
            ent -= avg[e] * logf(avg[e] + 1e-8f);
            float d = avg[e] - 0.2f;
            l2 += d * d;
        }
        l2 *= (1.0f / 5.0f);
        aux[0] = -ent * 0.01f + 0.01f * l2;
    }
}

// ---------------------------------------------------------------------------
// Fully fused expert kernel (traj + score), expert-parallel, 48 KB LDS:
// h1/h2/s1/s2/f32-staging all share ONE 32 KB buffer (hb).
// ---------------------------------------------------------------------------
__global__ __launch_bounds__(512, 2)
void expert_fused(const u16* __restrict__ xb, const u16* __restrict__ wtb,
                  const float* __restrict__ biasp, float* __restrict__ out,
                  float* __restrict__ shtraj, float* __restrict__ shscore)
{
    __shared__ u16 xs[64 * 128];   // 16 KB (x tile; also S1 A-operand)
    __shared__ u16 hb[64 * 256];   // 32 KB multi-role: h1 -> h2 -> s1/s2 -> f32 staging
    float* hbf = (float*)hb;
    u16* s1p = hb;                 // s1 [64,128] bf16, 16 KB
    u16* s2p = hb + 64 * 128;      // s2 [64,64]  bf16,  8 KB

    const int tid  = threadIdx.x;
    const int lane = tid & 63;
    const int wave = tid >> 6;          // 0..7
    const int row0 = blockIdx.x * 64;
    const int e    = blockIdx.y;        // expert 0..5 (5 = shared)
    const int frow = lane & 15;
    const int kgrp = lane >> 4;         // 0..3
    const int c0   = wave * 32;         // L1/L2 col slice

    // stage x tile (linear LDS dest, inverse-swizzled global source)
    #pragma unroll
    for (int i = 0; i < 2; ++i) {
        const int idx = i * 512 + tid;
        const int r = idx >> 4, c = idx & 15;
        gload16(xb + (size_t)(row0 + r) * 128 + ((c ^ (r & 7)) << 3), &xs[idx * 8]);
    }

    const int col3 = wave * 16 + kgrp * 4;                       // L3 output colbase
    const int r3   = (wave * 16 + frow) < 120 ? (wave * 16 + frow) : 119;

    // prefetch L1 weight fragments
    s16x8 wf1[4][2];
    {
        const u16* w1p = wtb + O_T1 + e * 32768;
        #pragma unroll
        for (int n = 0; n < 2; ++n) {
            const u16* p = w1p + (size_t)(c0 + n * 16 + frow) * 128 + kgrp * 8;
            #pragma unroll
            for (int ks = 0; ks < 4; ++ks) wf1[ks][n] = *(const s16x8*)(p + ks * 32);
        }
    }
    SBAR();

    __syncthreads();   // B0: xs ready (drains vmcnt)

    // ---------- L1: xs[64,128] -> h1 (into hb) ----------
    f32x4 acc1[4][2] = {};
    #pragma unroll
    for (int ks = 0; ks < 4; ++ks)
        #pragma unroll
        for (int m = 0; m < 4; ++m) {
            const s16x8 a = lds_frag(xs, 128, m * 16 + frow, ks * 4 + kgrp);
            #pragma unroll
            for (int n = 0; n < 2; ++n)
                acc1[m][n] = MFMA16(wf1[ks][n], a, acc1[m][n]);
        }

    // issue L2 first-half weight + L1 bias prefetch, pinned before stores
    const u16* w2p = wtb + O_T2 + e * 65536;
    s16x8 wf2a[4][2];
    f32x4 bb1[2];
    #pragma unroll
    for (int n = 0; n < 2; ++n) {
        const u16* p = w2p + (size_t)(c0 + n * 16 + frow) * 256 + kgrp * 8;
        #pragma unroll
        for (int ks = 0; ks < 4; ++ks) wf2a[ks][n] = *(const s16x8*)(p + ks * 32);
        bb1[n] = *(const f32x4*)&biasp[OB_T1 + e * 256 + c0 + n * 16 + kgrp * 4];
    }
    SBAR();

    {   // store h1 (+bias+gelu) -> hb
        #pragma unroll
        for (int n = 0; n < 2; ++n) {
            const int colb = c0 + n * 16 + kgrp * 4;
            #pragma unroll
            for (int m = 0; m < 4; ++m)
                lds_store4(hb, 256, m * 16 + frow, colb,
                           gelu_f(acc1[m][n][0] + bb1[n][0]),
                           gelu_f(acc1[m][n][1] + bb1[n][1]),
                           gelu_f(acc1[m][n][2] + bb1[n][2]),
                           gelu_f(acc1[m][n][3] + bb1[n][3]));
        }
    }
    __syncthreads();   // B1: h1 ready

    // issue L2 second-half weight prefetch
    s16x8 wf2b[4][2];
    #pragma unroll
    for (int n = 0; n < 2; ++n) {
        const u16* p = w2p + (size_t)(c0 + n * 16 + frow) * 256 + 128 + kgrp * 8;
        #pragma unroll
        for (int ks = 0; ks < 4; ++ks) wf2b[ks][n] = *(const s16x8*)(p + ks * 32);
    }
    SBAR();

    // ---------- L2: hb(h1) -> acc2 regs, K=256 ----------
    f32x4 acc2[4][2] = {};
    #pragma unroll
    for (int ks = 0; ks < 4; ++ks)
        #pragma unroll
        for (int m = 0; m < 4; ++m) {
            const s16x8 a = lds_frag(hb, 256, m * 16 + frow, ks * 4 + kgrp);
            #pragma unroll
            for (int n = 0; n < 2; ++n)
                acc2[m][n] = MFMA16(wf2a[ks][n], a, acc2[m][n]);
        }
    #pragma unroll
    for (int ks = 0; ks < 4; ++ks)
        #pragma unroll
        for (int m = 0; m < 4; ++m) {
            const s16x8 a = lds_frag(hb, 256, m * 16 + frow, (ks + 4) * 4 + kgrp);
            #pragma unroll
            for (int n = 0; n < 2; ++n)
                acc2[m][n] = MFMA16(wf2b[ks][n], a, acc2[m][n]);
        }

    // issue L3 weight + L2 bias prefetch
    s16x8 wf3[8];
    f32x4 bb2[2];
    {
        const u16* w3p = wtb + O_T3 + e * 30720 + (size_t)r3 * 256 + kgrp * 8;
        #pragma unroll
        for (int ks = 0; ks < 8; ++ks) wf3[ks] = *(const s16x8*)(w3p + ks * 32);
        #pragma unroll
        for (int n = 0; n < 2; ++n)
            bb2[n] = *(const f32x4*)&biasp[OB_T2 + e * 256 + c0 + n * 16 + kgrp * 4];
    }
    SBAR();
    __syncthreads();   // B2: all h1 reads done -> hb reusable

    {   // store h2 (+bias+gelu) -> hb
        #pragma unroll
        for (int n = 0; n < 2; ++n) {
            const int colb = c0 + n * 16 + kgrp * 4;
            #pragma unroll
            for (int m = 0; m < 4; ++m)
                lds_store4(hb, 256, m * 16 + frow, colb,
                           gelu_f(acc2[m][n][0] + bb2[n][0]),
                           gelu_f(acc2[m][n][1] + bb2[n][1]),
                           gelu_f(acc2[m][n][2] + bb2[n][2]),
                           gelu_f(acc2[m][n][3] + bb2[n][3]));
        }
    }
    __syncthreads();   // B3: h2 ready

    // issue S1 weight + L3 bias prefetch (complete under L3 MFMAs)
    s16x8 wfs1[4];
    f32x4 bb3 = *(const f32x4u*)&biasp[OB_T3 + e * 120 + (col3 < 120 ? col3 : 116)];
    {
        const u16* p = wtb + O_S1 + e * 16384 + (size_t)(wave * 16 + frow) * 128 + kgrp * 8;
        #pragma unroll
        for (int ks = 0; ks < 4; ++ks) wfs1[ks] = *(const s16x8*)(p + ks * 32);
    }
    SBAR();

    // ---------- L3: hb(h2) -> acc3 regs (held through the score phase) ----------
    f32x4 acc3[4] = {};
    #pragma unroll
    for (int ks = 0; ks < 8; ++ks)
        #pragma unroll
        for (int m = 0; m < 4; ++m) {
            const s16x8 a = lds_frag(hb, 256, m * 16 + frow, ks * 4 + kgrp);
            acc3[m] = MFMA16(wf3[ks], a, acc3[m]);
        }
    __syncthreads();   // B4: all h2 reads done -> hb reusable for s1/s2

    // ---------- S1: xs -> s1 (hb[0:16K]) ----------
    f32x4 accs1[4] = {};
    #pragma unroll
    for (int ks = 0; ks < 4; ++ks)
        #pragma unroll
        for (int m = 0; m < 4; ++m) {
            const s16x8 a = lds_frag(xs, 128, m * 16 + frow, ks * 4 + kgrp);
            accs1[m] = MFMA16(wfs1[ks], a, accs1[m]);
        }
    // issue S2 weight + S1 bias prefetch
    s16x8 wfs2[4];
    f32x4 bbs1;
    {
        const u16* p = wtb + O_S2 + e * 8192 + (size_t)((wave & 3) * 16 + frow) * 128 + kgrp * 8;
        #pragma unroll
        for (int ks = 0; ks < 4; ++ks) wfs2[ks] = *(const s16x8*)(p + ks * 32);
        bbs1 = *(const f32x4*)&biasp[OB_S1 + e * 128 + wave * 16 + kgrp * 4];
    }
    SBAR();
    {
        const int colb = wave * 16 + kgrp * 4;
        #pragma unroll
        for (int m = 0; m < 4; ++m)
            lds_store4(s1p, 128, m * 16 + frow, colb,
                       gelu_f(accs1[m][0] + bbs1[0]),
                       gelu_f(accs1[m][1] + bbs1[1]),
                       gelu_f(accs1[m][2] + bbs1[2]),
                       gelu_f(accs1[m][3] + bbs1[3]));
    }
    __syncthreads();   // B5: s1 ready

    // ---------- S2: s1 -> s2 (hb[16K:24K]) (waves 0-3) ----------
    if (wave < 4) {
        f32x4 accs2[4] = {};
        #pragma unroll
        for (int ks = 0; ks < 4; ++ks)
            #pragma unroll
            for (int m = 0; m < 4; ++m) {
                const s16x8 a = lds_frag(s1p, 128, m * 16 + frow, ks * 4 + kgrp);
                accs2[m] = MFMA16(wfs2[ks], a, accs2[m]);
            }
        const int colb = wave * 16 + kgrp * 4;
        const f32x4 bb = *(const f32x4*)&biasp[OB_S2 + e * 64 + colb];
        #pragma unroll
        for (int m = 0; m < 4; ++m)
            lds_store4(s2p, 64, m * 16 + frow, colb,
                       gelu_f(accs2[m][0] + bb[0]),
                       gelu_f(accs2[m][1] + bb[1]),
                       gelu_f(accs2[m][2] + bb[2]),
                       gelu_f(accs2[m][3] + bb[3]));
    }
    __syncthreads();   // B6: s2 ready

    // ---------- S3: dot64 per token (512 thr = 64 tok x 8 kc) ----------
    {
        const int tok = tid >> 3;          // 0..63
        const int kc  = tid & 7;           // 0..7
        const float* w3s = biasp + OW_S3 + e * 64 + kc * 8;
        const s16x8 v = lds_frag(s2p, 64, tok, kc);
        float p = 0.f;
        #pragma unroll
        for (int j = 0; j < 8; ++j) p = fmaf(bf2f((u16)v[j]), w3s[j], p);
        p += __shfl_xor(p, 1);
        p += __shfl_xor(p, 2);
        p += __shfl_xor(p, 4);
        if (kc == 0) {
            const float val = p + biasp[OB_S3 + e];
            if (e < 5) out[OFF_SCOREALL + (size_t)e * N_TOK + row0 + tok] = val;
            else       shscore[row0 + tok] = val;
        }
    }
    __syncthreads();   // B7: s2 reads done -> hb reusable for f32 staging

    // ---------- stage traj f32 tile [64][124] (padded: bank spread) ----------
    if (col3 < 120) {
        #pragma unroll
        for (int m = 0; m < 4; ++m) {
            f32x4 v;
            #pragma unroll
            for (int j = 0; j < 4; ++j) v[j] = acc3[m][j] + bb3[j];
            *(f32x4*)&hbf[(m * 16 + frow) * 124 + col3] = v;
        }
    }
    __syncthreads();   // B8: staging complete

    // ---- 16B-ALIGNED PLAIN contiguous copy of 7680 floats ----
    {
        float* dst = (e < 5) ? out + OFF_TRAJALL + ((size_t)e * N_TOK + row0) * 120
                             : shtraj + (size_t)row0 * 120;
        const int head = (int)((16 - (((size_t)dst) & 15)) & 15) >> 2;  // 0..3 floats
        const int nvec = (7680 - head) >> 2;
        const int tail = 7680 - head - (nvec << 2);
        if (tid < head) {
            const int t0i = tid;
            dst[t0i] = hbf[(t0i / 120) * 124 + (t0i % 120)];
        }
        if (tid >= 8 && tid < 8 + tail) {
            const int t0i = 7680 - tail + (tid - 8);
            dst[t0i] = hbf[(t0i / 120) * 124 + (t0i % 120)];
        }
        #pragma unroll
        for (int i = 0; i < 4; ++i) {
            const int v = i * 512 + tid;
            if (v < nvec) {
                const int q = head + v * 4;
                const int tok = q / 120;
                const int colq = q - tok * 120;
                // q is 4-aligned only when head==0; handle general case scalar-wise
                f32x4 val;
                #pragma unroll
                for (int j = 0; j < 4; ++j) {
                    const int qq = q + j;
                    const int tk = qq / 120;
                    val[j] = hbf[tk * 124 + (qq - tk * 120)];
                }
                (void)tok; (void)colq;
                *(f32x4*)(dst + q) = val;     // aligned plain store
            }
        }
    }
}

// ---------------------------------------------------------------------------
// Final combine: traj = 0.3*shared + 0.7*(p0*traj[i0]+p1*traj[i1]); also score.
// ---------------------------------------------------------------------------
__global__ __launch_bounds__(256)
void combine_all(const float* __restrict__ trajall, const float* __restrict__ shtraj,
                 const float* __restrict__ scoreall, const float* __restrict__ shscore,
                 const float* __restrict__ tp, const int* __restrict__ ti,
                 float* __restrict__ ftraj, float* __restrict__ fscore)
{
    const int i4 = blockIdx.x * 256 + threadIdx.x;   // < N*30
    const int n  = i4 / 30;
    const int q4 = (i4 - n * 30) * 4;
    const int i0 = ti[n * 2], i1 = ti[n * 2 + 1];
    const float p0 = tp[n * 2], p1 = tp[n * 2 + 1];

    const f32x4 a = *(const f32x4u*)&trajall[((size_t)i0 * N_TOK + n) * 120 + q4];
    const f32x4 b = *(const f32x4u*)&trajall[((size_t)i1 * N_TOK + n) * 120 + q4];
    const f32x4 s = *(const f32x4*)&shtraj[(size_t)n * 120 + q4];
    f32x4 r;
    #pragma unroll
    for (int j = 0; j < 4; ++j)
        r[j] = 0.3f * s[j] + 0.7f * (p0 * a[j] + p1 * b[j]);
    *(f32x4*)&ftraj[(size_t)n * 120 + q4] = r;

    if (q4 == 0) {
        const float sa = scoreall[(size_t)i0 * N_TOK + n];
        const float sb = scoreall[(size_t)i1 * N_TOK + n];
        fscore[n] = 0.3f * shscore[n] + 0.7f * (p0 * sa + p1 * sb);
    }
}

// Weight convert+transpose via LDS tiles (coalesced both sides):
// src fp32 [nz][K][H] -> dst bf16 [nz][H][K]
struct WDesc { const float* src; u32 dstOff; int K, H, nz; };
struct WTable { WDesc d[10]; };

__global__ __launch_bounds__(256)
void convert_w(WTable t, u16* __restrict__ dst)
{
    const WDesc dd = t.d[blockIdx.y];
    const int tilesK = dd.K >> 5;
    const int tilesH = (dd.H + 31) >> 5;
    const int tt = blockIdx.x;
    if (tt >= tilesK * tilesH * dd.nz) return;
    const int e  = tt / (tilesK * tilesH);
    const int r  = tt - e * (tilesK * tilesH);
    const int th = r / tilesK;
    const int tk = r - th * tilesK;

    __shared__ float tile[32][33];
    const int tx = threadIdx.x & 31;
    const int ty = threadIdx.x >> 5;     // 0..7

    #pragma unroll
    for (int i = 0; i < 4; ++i) {
        const int k = tk * 32 + ty + i * 8;
        const int h = th * 32 + tx;
        tile[ty + i * 8][tx] = (h < dd.H)
            ? dd.src[((size_t)e * dd.K + k) * dd.H + h] : 0.0f;
    }
    __syncthreads();
    #pragma unroll
    for (int i = 0; i < 4; ++i) {
        const int h = th * 32 + ty + i * 8;
        const int k = tk * 32 + tx;
        if (h < dd.H)
            dst[dd.dstOff + ((size_t)e * dd.H + h) * dd.K + k] = f2bf(tile[tx][ty + i * 8]);
    }
}

// Flat fp32 gather-pack (biases + score L3 weights)
struct CDesc { const float* src; u32 dstOff; u32 n; };
struct CTable { CDesc d[14]; };

__global__ __launch_bounds__(256)
void pack_f32(CTable t, float* __restrict__ dst)
{
    const CDesc dd = t.d[blockIdx.y];
    const u32 i = blockIdx.x * 256 + threadIdx.x;
    if (i < dd.n) dst[dd.dstOff + i] = dd.src[i];
}

// ---------------------------------------------------------------------------
extern "C" void kernel_launch(void* const* d_in, const int* in_sizes, int n_in,
                              void* d_out, int out_size, void* d_ws, size_t ws_size,
                              hipStream_t stream)
{
    (void)in_sizes; (void)n_in; (void)out_size; (void)ws_size;

    const float* x   = (const float*)d_in[0];
    const float* rw1 = (const float*)d_in[1];
    const float* rb1 = (const float*)d_in[2];
    const float* rw2 = (const float*)d_in[3];
    const float* rb2 = (const float*)d_in[4];
    const float* rw3 = (const float*)d_in[5];
    const float* rb3 = (const float*)d_in[6];

    float* out = (float*)d_out;
    char* ws = (char*)d_ws;

    // ---- workspace layout ----
    u16*   xb      = (u16*)(ws);                   // [N,128] bf16   12,582,912 B
    u16*   wtb     = (u16*)(ws + 12582912);        // packed bf16 W   1,843,200 B
    float* biasp   = (float*)(ws + 14426112);      // packed fp32        21,504 B
    float* part    = (float*)(ws + 14447616);      // [1536,5]           30,720 B
    float* tp      = (float*)(ws + 14478336);      // [N,2]
    int*   ti      = (int*)  (ws + 14871552);      // [N,2]
    float* shscore = (float*)(ws + 15264768);      // [N] fp32          196,608 B
    float* shtraj  = (float*)(ws + 15461376);      // [N,120] fp32   23,592,960 B

    const dim3 blk(256);

    // ---- fused fp32 router (also emits xb bf16) ----
    router_fused<<<dim3(N_TOK / 32), dim3(512), 0, stream>>>(
        x, rw1, rb1, rw2, rb2, rw3, rb3, xb,
        out + OFF_LOGITS, out + OFF_IDX, tp, ti, part);
    aux_kernel<<<dim3(1), blk, 0, stream>>>(part, out + OFF_AUX);

    // ---- weight conversion / packing ----
    {
        WTable t;
        t.d[0] = { (const float*)d_in[19], O_T1,              128, 256, 5 };
        t.d[1] = { (const float*)d_in[7],  O_T1 + 5 * 32768,  128, 256, 1 };
        t.d[2] = { (const float*)d_in[21], O_T2,              256, 256, 5 };
        t.d[3] = { (const float*)d_in[9],  O_T2 + 5 * 65536,  256, 256, 1 };
        t.d[4] = { (const float*)d_in[23], O_T3,              256, 120, 5 };
        t.d[5] = { (const float*)d_in[11], O_T3 + 5 * 30720,  256, 120, 1 };
        t.d[6] = { (const float*)d_in[25], O_S1,              128, 128, 5 };
        t.d[7] = { (const float*)d_in[13], O_S1 + 5 * 16384,  128, 128, 1 };
        t.d[8] = { (const float*)d_in[27], O_S2,              128,  64, 5 };
        t.d[9] = { (const float*)d_in[15], O_S2 + 5 * 8192,   128,  64, 1 };
        convert_w<<<dim3(320, 10), blk, 0, stream>>>(t, wtb);
    }
    {
        CTable t;
        t.d[0]  = { (const float*)d_in[20], OB_T1,        1280 };
        t.d[1]  = { (const float*)d_in[8],  OB_T1 + 1280,  256 };
        t.d[2]  = { (const float*)d_in[22], OB_T2,        1280 };
        t.d[3]  = { (const float*)d_in[10], OB_T2 + 1280,  256 };
        t.d[4]  = { (const float*)d_in[24], OB_T3,         600 };
        t.d[5]  = { (const float*)d_in[12], OB_T3 + 600,   120 };
        t.d[6]  = { (const float*)d_in[26], OB_S1,         640 };
        t.d[7]  = { (const float*)d_in[14], OB_S1 + 640,   128 };
        t.d[8]  = { (const float*)d_in[28], OB_S2,         320 };
        t.d[9]  = { (const float*)d_in[16], OB_S2 + 320,    64 };
        t.d[10] = { (const float*)d_in[29], OW_S3,         320 };
        t.d[11] = { (const float*)d_in[17], OW_S3 + 320,    64 };
        t.d[12] = { (const float*)d_in[30], OB_S3,           5 };
        t.d[13] = { (const float*)d_in[18], OB_S3 + 5,       1 };
        pack_f32<<<dim3(5, 14), blk, 0, stream>>>(t, biasp);
    }

    // ---- fully fused expert path (blockIdx.y = expert, 5 unshared + shared) ----
    expert_fused<<<dim3(N_TOK / 64, 6), dim3(512), 0, stream>>>(
        xb, wtb, biasp, out, shtraj, shscore);

    // ---- final combine (traj + score) ----
    combine_all<<<dim3(N_TOK * 30 / 256), blk, 0, stream>>>(
        out + OFF_TRAJALL, shtraj, out + OFF_SCOREALL, shscore,
        tp, ti, out + OFF_TRAJ, out + OFF_SCORE);
}

// Round 16
// 389.925 us; speedup vs baseline: 1.0677x; 1.0677x over previous
//
#include <hip/hip_runtime.h>
#include <hip/hip_bf16.h>
#include <cstdint>
#include <cstddef>

// Problem constants
static constexpr int N_TOK = 49152;     // B*M = 8192*6
// d_out offsets (floats), outputs concatenated in reference return order
static constexpr size_t OFF_TRAJ     = 0;          // [N,120]
static constexpr size_t OFF_SCORE    = 5898240;    // [N]
static constexpr size_t OFF_LOGITS   = 5947392;    // [N,5]
static constexpr size_t OFF_IDX      = 6193152;    // [N,2]  (ints stored as floats)
static constexpr size_t OFF_AUX      = 6291456;    // [1]
static constexpr size_t OFF_TRAJALL  = 6291457;    // [5,N,120]
static constexpr size_t OFF_SCOREALL = 35782657;   // [5,N]

typedef short s16x8 __attribute__((ext_vector_type(8)));
typedef float f32x4 __attribute__((ext_vector_type(4)));
typedef f32x4 f32x4u __attribute__((aligned(4)));   // reduced-alignment variant
typedef unsigned int u32;
typedef unsigned short u16;

// packed bf16 weight offsets (u16 elems): [6][H][K] per layer (experts 0-4, shared=5)
static constexpr u32 O_T1 = 0,      O_T2 = 196608, O_T3 = 589824;
static constexpr u32 O_S1 = 774144, O_S2 = 872448;
// packed fp32 offsets (floats)
static constexpr u32 OB_T1 = 0, OB_T2 = 1536, OB_T3 = 3072, OB_S1 = 3792, OB_S2 = 4560;
static constexpr u32 OW_S3 = 4944, OB_S3 = 5328;

// exact gelu (router path: logits feed exact-match topk)
__device__ __forceinline__ float gelu_exact(float x) {
    return 0.5f * x * (1.0f + erff(x * 0.70710678118654752440f));
}
// fast gelu: x*sigmoid(1.5957691*(x+0.044715x^3)); rcp instead of exact division
__device__ __forceinline__ float gelu_f(float x) {
    const float x2 = x * x;
    const float u  = x * fmaf(0.07135486172f, x2, 1.5957691216057308f);
    const float t  = __expf(-u);
    return x * __builtin_amdgcn_rcpf(1.0f + t);
}
__device__ __forceinline__ float bf2f(u16 u) {
    return __uint_as_float(((u32)u) << 16);
}
__device__ __forceinline__ u16 f2bf(float v) {
    return ((__hip_bfloat16_raw)__float2bfloat16(v)).x;
}
__device__ __forceinline__ void gload16(const u16* g, u16* l) {
    __builtin_amdgcn_global_load_lds(
        (const __attribute__((address_space(1))) u32*)g,
        (__attribute__((address_space(3))) u32*)l, 16, 0, 0);
}
#define MFMA16(a, b, c) __builtin_amdgcn_mfma_f32_16x16x32_bf16(a, b, c, 0, 0, 0)
#define SBAR() __builtin_amdgcn_sched_barrier(0)

// swizzled LDS fragment read: logical (row r, 16B-chunk c) at slot c^(r&mask)
// 4-bit mask spreads 16 fragment rows over 16 distinct 16B slots (r&7 left
// frow / frow+8 in the SAME slot -> 2-way bank conflict on every b128 op).
__device__ __forceinline__ s16x8 lds_frag(const u16* buf, int RBu16, int r, int c, int mask) {
    return *(const s16x8*)&buf[r * RBu16 + ((c ^ (r & mask)) << 3)];
}
// swizzled 8B LDS store of 4 consecutive bf16 cols (colb % 4 == 0)
__device__ __forceinline__ void lds_store4(u16* buf, int RBu16, int r, int colb, int mask,
                                           float v0, float v1, float v2, float v3) {
    const int ch = (colb >> 3) ^ (r & mask);
    ushort4 st = { f2bf(v0), f2bf(v1), f2bf(v2), f2bf(v3) };
    *(ushort4*)&buf[r * RBu16 + ch * 8 + (colb & 7)] = st;
}

// ---------------------------------------------------------------------------
// fp32 tile GEMM (router L1/L2 only; topk_idx needs fp32-exact logits).
// K-chunk 32; 33 KB LDS.
// ---------------------------------------------------------------------------
template<bool GELU>
__global__ __launch_bounds__(256)
void mlp_gemm(const float* __restrict__ A, const float* __restrict__ W,
              const float* __restrict__ bias, float* __restrict__ C,
              int Kd, int H)
{
    __shared__ float As[32][128];
    __shared__ float Ws[32][132];

    const int tid  = threadIdx.x;
    const int tx   = tid & 15;
    const int ty   = tid >> 4;
    const int row0 = blockIdx.x * 128;
    const int col0 = blockIdx.y * 128;
    const int lm = tid >> 1;
    const int lk = (tid & 1) * 16;

    float acc[8][8] = {};

    for (int k0 = 0; k0 < Kd; k0 += 32) {
        {
            const float* src = A + (size_t)(row0 + lm) * Kd + k0 + lk;
            #pragma unroll
            for (int q = 0; q < 4; ++q) {
                float4 f = *(const float4*)(src + q * 4);
                As[lk + q * 4 + 0][lm] = f.x;
                As[lk + q * 4 + 1][lm] = f.y;
                As[lk + q * 4 + 2][lm] = f.z;
                As[lk + q * 4 + 3][lm] = f.w;
            }
        }
        {
            #pragma unroll
            for (int q = 0; q < 2; ++q) {
                const float* wsrc = W + (size_t)(k0 + ty + q * 16) * H + col0 + tx * 8;
                float4 g0 = *(const float4*)wsrc;
                float4 g1 = *(const float4*)(wsrc + 4);
                *(float4*)&Ws[ty + q * 16][tx * 8]     = g0;
                *(float4*)&Ws[ty + q * 16][tx * 8 + 4] = g1;
            }
        }
        __syncthreads();
        #pragma unroll
        for (int kk = 0; kk < 32; ++kk) {
            float a[8], w[8];
            *(float4*)&a[0] = *(const float4*)&As[kk][ty * 8];
            *(float4*)&a[4] = *(const float4*)&As[kk][ty * 8 + 4];
            *(float4*)&w[0] = *(const float4*)&Ws[kk][tx * 8];
            *(float4*)&w[4] = *(const float4*)&Ws[kk][tx * 8 + 4];
            #pragma unroll
            for (int i = 0; i < 8; ++i)
                #pragma unroll
                for (int j = 0; j < 8; ++j)
                    acc[i][j] = fmaf(a[i], w[j], acc[i][j]);
        }
        __syncthreads();
    }

    #pragma unroll
    for (int i = 0; i < 8; ++i) {
        const int r = row0 + ty * 8 + i;
        #pragma unroll
        for (int j = 0; j < 8; ++j) {
            const int c = col0 + tx * 8 + j;
            float v = acc[i][j] + bias[c];
            if (GELU) v = gelu_exact(v);
            C[(size_t)r * H + c] = v;
        }
    }
}

// ---------------------------------------------------------------------------
// Router L3 + softmax partials + top-2 (fused).
// ---------------------------------------------------------------------------
__global__ __launch_bounds__(256)
void router_l3post(const float* __restrict__ rh2, const float* __restrict__ w3,
                   const float* __restrict__ b3, float* __restrict__ logits,
                   float* __restrict__ oidx, float* __restrict__ tp,
                   int* __restrict__ ti, float* __restrict__ part)
{
    __shared__ float w3s[640];
    __shared__ float red[256];
    const int tid = threadIdx.x;
    for (int i = tid; i < 640; i += 256) w3s[i] = w3[i];
    __syncthreads();

    const int n = blockIdx.x * 256 + tid;
    const float* h = rh2 + (size_t)n * 128;

    float l[5];
    #pragma unroll
    for (int e = 0; e < 5; ++e) l[e] = b3[e];
    for (int k = 0; k < 128; k += 4) {
        float4 hv = *(const float4*)(h + k);
        #pragma unroll
        for (int e = 0; e < 5; ++e) {
            l[e] = fmaf(hv.x, w3s[(k + 0) * 5 + e], l[e]);
            l[e] = fmaf(hv.y, w3s[(k + 1) * 5 + e], l[e]);
            l[e] = fmaf(hv.z, w3s[(k + 2) * 5 + e], l[e]);
            l[e] = fmaf(hv.w, w3s[(k + 3) * 5 + e], l[e]);
        }
    }
    #pragma unroll
    for (int e = 0; e < 5; ++e) logits[(size_t)n * 5 + e] = l[e];

    // full softmax (aux loss partials)
    float m = l[0];
    #pragma unroll
    for (int e = 1; e < 5; ++e) m = fmaxf(m, l[e]);
    float p[5], s = 0.f;
    #pragma unroll
    for (int e = 0; e < 5; ++e) { p[e] = expf(l[e] - m); s += p[e]; }
    const float inv = 1.0f / s;

    #pragma unroll
    for (int e = 0; e < 5; ++e) {
        red[tid] = p[e] * inv;
        __syncthreads();
        for (int off = 128; off > 0; off >>= 1) {
            if (tid < off) red[tid] += red[tid + off];
            __syncthreads();
        }
        if (tid == 0) part[blockIdx.x * 5 + e] = red[0];
        __syncthreads();
    }

    // top-2 (ties keep lower index, matching jax.lax.top_k)
    int i0 = 0; float v0 = l[0];
    #pragma unroll
    for (int e = 1; e < 5; ++e) if (l[e] > v0) { v0 = l[e]; i0 = e; }
    int i1 = -1; float v1 = -1e30f;
    #pragma unroll
    for (int e = 0; e < 5; ++e) if (e != i0 && l[e] > v1) { v1 = l[e]; i1 = e; }

    const float t  = expf(v1 - v0);
    const float q0 = 1.0f / (1.0f + t);
    const float q1 = t / (1.0f + t);

    oidx[(size_t)n * 2]     = (float)i0;
    oidx[(size_t)n * 2 + 1] = (float)i1;
    tp[n * 2] = q0; tp[n * 2 + 1] = q1;
    ti[n * 2] = i0; ti[n * 2 + 1] = i1;
}

__global__ __launch_bounds__(256)
void aux_kernel(const float* __restrict__ part, float* __restrict__ aux)
{
    __shared__ float avg[5];
    const int tid = threadIdx.x;
    if (tid < 5) {
        float s = 0.f;
        for (int b = 0; b < 192; ++b) s += part[b * 5 + tid];
        avg[tid] = s / (float)N_TOK;
    }
    __syncthreads();
    if (tid == 0) {
        float ent = 0.f, l2 = 0.f;
        #pragma unroll
        for (int e = 0; e < 5; ++e) {
            ent -= avg[e] * logf(avg[e] + 1e-8f);
            float d = avg[e] - 0.2f;
            l2 += d * d;
        }
        l2 *= (1.0f / 5.0f);
        aux[0] = -ent * 0.01f + 0.01f * l2;
    }
}

// ---------------------------------------------------------------------------
// Fully fused expert kernel (traj + score), expert-parallel, 48 KB LDS.
// 4-bit XOR swizzle on all bf16 LDS tiles (conflict fix vs 3-bit in r13-15).
// ---------------------------------------------------------------------------
__global__ __launch_bounds__(512, 2)
void expert_fused(const u16* __restrict__ xb, const u16* __restrict__ wtb,
                  const float* __restrict__ biasp, float* __restrict__ out,
                  float* __restrict__ shtraj, float* __restrict__ shscore)
{
    __shared__ u16 xs[64 * 128];   // 16 KB (x tile; also S1 A-operand)
    __shared__ u16 hb[64 * 256];   // 32 KB multi-role: h1 -> h2 -> s1/s2 -> f32 staging
    float* hbf = (float*)hb;
    u16* s1p = hb;                 // s1 [64,128] bf16, 16 KB
    u16* s2p = hb + 64 * 128;      // s2 [64,64]  bf16,  8 KB

    const int tid  = threadIdx.x;
    const int lane = tid & 63;
    const int wave = tid >> 6;          // 0..7
    const int row0 = blockIdx.x * 64;
    const int e    = blockIdx.y;        // expert 0..5 (5 = shared)
    const int frow = lane & 15;
    const int kgrp = lane >> 4;         // 0..3
    const int c0   = wave * 32;         // L1/L2 col slice

    // stage x tile (linear LDS dest, inverse-swizzled global source, mask 15)
    #pragma unroll
    for (int i = 0; i < 2; ++i) {
        const int idx = i * 512 + tid;
        const int r = idx >> 4, c = idx & 15;
        gload16(xb + (size_t)(row0 + r) * 128 + ((c ^ (r & 15)) << 3), &xs[idx * 8]);
    }

    const int col3 = wave * 16 + kgrp * 4;                       // L3 output colbase
    const int r3   = (wave * 16 + frow) < 120 ? (wave * 16 + frow) : 119;

    // prefetch L1 weight fragments
    s16x8 wf1[4][2];
    {
        const u16* w1p = wtb + O_T1 + e * 32768;
        #pragma unroll
        for (int n = 0; n < 2; ++n) {
            const u16* p = w1p + (size_t)(c0 + n * 16 + frow) * 128 + kgrp * 8;
            #pragma unroll
            for (int ks = 0; ks < 4; ++ks) wf1[ks][n] = *(const s16x8*)(p + ks * 32);
        }
    }
    SBAR();

    __syncthreads();   // B0: xs ready (drains vmcnt)

    // ---------- L1: xs[64,128] -> h1 (into hb) ----------
    f32x4 acc1[4][2] = {};
    #pragma unroll
    for (int ks = 0; ks < 4; ++ks)
        #pragma unroll
        for (int m = 0; m < 4; ++m) {
            const s16x8 a = lds_frag(xs, 128, m * 16 + frow, ks * 4 + kgrp, 15);
            #pragma unroll
            for (int n = 0; n < 2; ++n)
                acc1[m][n] = MFMA16(wf1[ks][n], a, acc1[m][n]);
        }

    // issue L2 first-half weight + L1 bias prefetch, pinned before stores
    const u16* w2p = wtb + O_T2 + e * 65536;
    s16x8 wf2a[4][2];
    f32x4 bb1[2];
    #pragma unroll
    for (int n = 0; n < 2; ++n) {
        const u16* p = w2p + (size_t)(c0 + n * 16 + frow) * 256 + kgrp * 8;
        #pragma unroll
        for (int ks = 0; ks < 4; ++ks) wf2a[ks][n] = *(const s16x8*)(p + ks * 32);
        bb1[n] = *(const f32x4*)&biasp[OB_T1 + e * 256 + c0 + n * 16 + kgrp * 4];
    }
    SBAR();

    {   // store h1 (+bias+gelu) -> hb
        #pragma unroll
        for (int n = 0; n < 2; ++n) {
            const int colb = c0 + n * 16 + kgrp * 4;
            #pragma unroll
            for (int m = 0; m < 4; ++m)
                lds_store4(hb, 256, m * 16 + frow, colb, 15,
                           gelu_f(acc1[m][n][0] + bb1[n][0]),
                           gelu_f(acc1[m][n][1] + bb1[n][1]),
                           gelu_f(acc1[m][n][2] + bb1[n][2]),
                           gelu_f(acc1[m][n][3] + bb1[n][3]));
        }
    }
    __syncthreads();   // B1: h1 ready

    // issue L2 second-half weight prefetch
    s16x8 wf2b[4][2];
    #pragma unroll
    for (int n = 0; n < 2; ++n) {
        const u16* p = w2p + (size_t)(c0 + n * 16 + frow) * 256 + 128 + kgrp * 8;
        #pragma unroll
        for (int ks = 0; ks < 4; ++ks) wf2b[ks][n] = *(const s16x8*)(p + ks * 32);
    }
    SBAR();

    // ---------- L2: hb(h1) -> acc2 regs, K=256 ----------
    f32x4 acc2[4][2] = {};
    #pragma unroll
    for (int ks = 0; ks < 4; ++ks)
        #pragma unroll
        for (int m = 0; m < 4; ++m) {
            const s16x8 a = lds_frag(hb, 256, m * 16 + frow, ks * 4 + kgrp, 15);
            #pragma unroll
            for (int n = 0; n < 2; ++n)
                acc2[m][n] = MFMA16(wf2a[ks][n], a, acc2[m][n]);
        }
    #pragma unroll
    for (int ks = 0; ks < 4; ++ks)
        #pragma unroll
        for (int m = 0; m < 4; ++m) {
            const s16x8 a = lds_frag(hb, 256, m * 16 + frow, (ks + 4) * 4 + kgrp, 15);
            #pragma unroll
            for (int n = 0; n < 2; ++n)
                acc2[m][n] = MFMA16(wf2b[ks][n], a, acc2[m][n]);
        }

    // issue L3 weight + L2 bias prefetch
    s16x8 wf3[8];
    f32x4 bb2[2];
    {
        const u16* w3p = wtb + O_T3 + e * 30720 + (size_t)r3 * 256 + kgrp * 8;
        #pragma unroll
        for (int ks = 0; ks < 8; ++ks) wf3[ks] = *(const s16x8*)(w3p + ks * 32);
        #pragma unroll
        for (int n = 0; n < 2; ++n)
            bb2[n] = *(const f32x4*)&biasp[OB_T2 + e * 256 + c0 + n * 16 + kgrp * 4];
    }
    SBAR();
    __syncthreads();   // B2: all h1 reads done -> hb reusable

    {   // store h2 (+bias+gelu) -> hb
        #pragma unroll
        for (int n = 0; n < 2; ++n) {
            const int colb = c0 + n * 16 + kgrp * 4;
            #pragma unroll
            for (int m = 0; m < 4; ++m)
                lds_store4(hb, 256, m * 16 + frow, colb, 15,
                           gelu_f(acc2[m][n][0] + bb2[n][0]),
                           gelu_f(acc2[m][n][1] + bb2[n][1]),
                           gelu_f(acc2[m][n][2] + bb2[n][2]),
                           gelu_f(acc2[m][n][3] + bb2[n][3]));
        }
    }
    __syncthreads();   // B3: h2 ready

    // issue S1 weight + L3 bias prefetch (complete under L3 MFMAs)
    s16x8 wfs1[4];
    f32x4 bb3 = *(const f32x4u*)&biasp[OB_T3 + e * 120 + (col3 < 120 ? col3 : 116)];
    {
        const u16* p = wtb + O_S1 + e * 16384 + (size_t)(wave * 16 + frow) * 128 + kgrp * 8;
        #pragma unroll
        for (int ks = 0; ks < 4; ++ks) wfs1[ks] = *(const s16x8*)(p + ks * 32);
    }
    SBAR();

    // ---------- L3: hb(h2) -> acc3 regs (held through the score phase) ----------
    f32x4 acc3[4] = {};
    #pragma unroll
    for (int ks = 0; ks < 8; ++ks)
        #pragma unroll
        for (int m = 0; m < 4; ++m) {
            const s16x8 a = lds_frag(hb, 256, m * 16 + frow, ks * 4 + kgrp, 15);
            acc3[m] = MFMA16(wf3[ks], a, acc3[m]);
        }
    __syncthreads();   // B4: all h2 reads done -> hb reusable for s1/s2

    // ---------- S1: xs -> s1 (hb[0:16K]) ----------
    f32x4 accs1[4] = {};
    #pragma unroll
    for (int ks = 0; ks < 4; ++ks)
        #pragma unroll
        for (int m = 0; m < 4; ++m) {
            const s16x8 a = lds_frag(xs, 128, m * 16 + frow, ks * 4 + kgrp, 15);
            accs1[m] = MFMA16(wfs1[ks], a, accs1[m]);
        }
    // issue S2 weight + S1 bias prefetch
    s16x8 wfs2[4];
    f32x4 bbs1;
    {
        const u16* p = wtb + O_S2 + e * 8192 + (size_t)((wave & 3) * 16 + frow) * 128 + kgrp * 8;
        #pragma unroll
        for (int ks = 0; ks < 4; ++ks) wfs2[ks] = *(const s16x8*)(p + ks * 32);
        bbs1 = *(const f32x4*)&biasp[OB_S1 + e * 128 + wave * 16 + kgrp * 4];
    }
    SBAR();
    {
        const int colb = wave * 16 + kgrp * 4;
        #pragma unroll
        for (int m = 0; m < 4; ++m)
            lds_store4(s1p, 128, m * 16 + frow, colb, 15,
                       gelu_f(accs1[m][0] + bbs1[0]),
                       gelu_f(accs1[m][1] + bbs1[1]),
                       gelu_f(accs1[m][2] + bbs1[2]),
                       gelu_f(accs1[m][3] + bbs1[3]));
    }
    __syncthreads();   // B5: s1 ready

    // ---------- S2: s1 -> s2 (hb[16K:24K]) (waves 0-3) ----------
    if (wave < 4) {
        f32x4 accs2[4] = {};
        #pragma unroll
        for (int ks = 0; ks < 4; ++ks)
            #pragma unroll
            for (int m = 0; m < 4; ++m) {
                const s16x8 a = lds_frag(s1p, 128, m * 16 + frow, ks * 4 + kgrp, 15);
                accs2[m] = MFMA16(wfs2[ks], a, accs2[m]);
            }
        const int colb = wave * 16 + kgrp * 4;
        const f32x4 bb = *(const f32x4*)&biasp[OB_S2 + e * 64 + colb];
        #pragma unroll
        for (int m = 0; m < 4; ++m)
            lds_store4(s2p, 64, m * 16 + frow, colb, 7,
                       gelu_f(accs2[m][0] + bb[0]),
                       gelu_f(accs2[m][1] + bb[1]),
                       gelu_f(accs2[m][2] + bb[2]),
                       gelu_f(accs2[m][3] + bb[3]));
    }
    __syncthreads();   // B6: s2 ready

    // ---------- S3: dot64 per token (512 thr = 64 tok x 8 kc) ----------
    {
        const int tok = tid >> 3;          // 0..63
        const int kc  = tid & 7;           // 0..7
        const float* w3s = biasp + OW_S3 + e * 64 + kc * 8;
        const s16x8 v = lds_frag(s2p, 64, tok, kc, 7);
        float p = 0.f;
        #pragma unroll
        for (int j = 0; j < 8; ++j) p = fmaf(bf2f((u16)v[j]), w3s[j], p);
        p += __shfl_xor(p, 1);
        p += __shfl_xor(p, 2);
        p += __shfl_xor(p, 4);
        if (kc == 0) {
            const float val = p + biasp[OB_S3 + e];
            if (e < 5) out[OFF_SCOREALL + (size_t)e * N_TOK + row0 + tok] = val;
            else       shscore[row0 + tok] = val;
        }
    }
    __syncthreads();   // B7: s2 reads done -> hb reusable for f32 staging

    // ---------- stage traj f32 tile [64][124] (padded) ----------
    if (col3 < 120) {
        #pragma unroll
        for (int m = 0; m < 4; ++m) {
            f32x4 v;
            #pragma unroll
            for (int j = 0; j < 4; ++j) v[j] = acc3[m][j] + bb3[j];
            *(f32x4*)&hbf[(m * 16 + frow) * 124 + col3] = v;
        }
    }
    __syncthreads();   // B8: staging complete

    // ---- 16B-ALIGNED PLAIN contiguous copy of 7680 floats ----
    {
        float* dst = (e < 5) ? out + OFF_TRAJALL + ((size_t)e * N_TOK + row0) * 120
                             : shtraj + (size_t)row0 * 120;
        const int head = (int)((16 - (((size_t)dst) & 15)) & 15) >> 2;  // 0..3 floats
        const int nvec = (7680 - head) >> 2;
        const int tail = 7680 - head - (nvec << 2);
        if (tid < head) {
            const int t0i = tid;
            dst[t0i] = hbf[(t0i / 120) * 124 + (t0i % 120)];
        }
        if (tid >= 8 && tid < 8 + tail) {
            const int t0i = 7680 - tail + (tid - 8);
            dst[t0i] = hbf[(t0i / 120) * 124 + (t0i % 120)];
        }
        #pragma unroll
        for (int i = 0; i < 4; ++i) {
            const int v = i * 512 + tid;
            if (v < nvec) {
                const int q = head + v * 4;
                f32x4 val;
                #pragma unroll
                for (int j = 0; j < 4; ++j) {
                    const int qq = q + j;
                    const int tk = qq / 120;
                    val[j] = hbf[tk * 124 + (qq - tk * 120)];
                }
                *(f32x4*)(dst + q) = val;     // aligned plain store
            }
        }
    }
}

// ---------------------------------------------------------------------------
// Final combine: traj = 0.3*shared + 0.7*(p0*traj[i0]+p1*traj[i1]); also score.
// ---------------------------------------------------------------------------
__global__ __launch_bounds__(256)
void combine_all(const float* __restrict__ trajall, const float* __restrict__ shtraj,
                 const float* __restrict__ scoreall, const float* __restrict__ shscore,
                 const float* __restrict__ tp, const int* __restrict__ ti,
                 float* __restrict__ ftraj, float* __restrict__ fscore)
{
    const int i4 = blockIdx.x * 256 + threadIdx.x;   // < N*30
    const int n  = i4 / 30;
    const int q4 = (i4 - n * 30) * 4;
    const int i0 = ti[n * 2], i1 = ti[n * 2 + 1];
    const float p0 = tp[n * 2], p1 = tp[n * 2 + 1];

    const f32x4 a = *(const f32x4u*)&trajall[((size_t)i0 * N_TOK + n) * 120 + q4];
    const f32x4 b = *(const f32x4u*)&trajall[((size_t)i1 * N_TOK + n) * 120 + q4];
    const f32x4 s = *(const f32x4*)&shtraj[(size_t)n * 120 + q4];
    f32x4 r;
    #pragma unroll
    for (int j = 0; j < 4; ++j)
        r[j] = 0.3f * s[j] + 0.7f * (p0 * a[j] + p1 * b[j]);
    *(f32x4*)&ftraj[(size_t)n * 120 + q4] = r;

    if (q4 == 0) {
        const float sa = scoreall[(size_t)i0 * N_TOK + n];
        const float sb = scoreall[(size_t)i1 * N_TOK + n];
        fscore[n] = 0.3f * shscore[n] + 0.7f * (p0 * sa + p1 * sb);
    }
}

// ---------------------------------------------------------------------------
__global__ __launch_bounds__(256)
void convert_x(const float* __restrict__ x, u16* __restrict__ xb)
{
    const size_t i = ((size_t)blockIdx.x * 256 + threadIdx.x) * 4;
    float4 v = *(const float4*)(x + i);
    ushort4 o;
    o.x = f2bf(v.x); o.y = f2bf(v.y); o.z = f2bf(v.z); o.w = f2bf(v.w);
    *(ushort4*)(xb + i) = o;
}

// Weight convert+transpose via LDS tiles (coalesced both sides):
// src fp32 [nz][K][H] -> dst bf16 [nz][H][K]
struct WDesc { const float* src; u32 dstOff; int K, H, nz; };
struct WTable { WDesc d[10]; };

__global__ __launch_bounds__(256)
void convert_w(WTable t, u16* __restrict__ dst)
{
    const WDesc dd = t.d[blockIdx.y];
    const int tilesK = dd.K >> 5;
    const int tilesH = (dd.H + 31) >> 5;
    const int tt = blockIdx.x;
    if (tt >= tilesK * tilesH * dd.nz) return;
    const int e  = tt / (tilesK * tilesH);
    const int r  = tt - e * (tilesK * tilesH);
    const int th = r / tilesK;
    const int tk = r - th * tilesK;

    __shared__ float tile[32][33];
    const int tx = threadIdx.x & 31;
    const int ty = threadIdx.x >> 5;     // 0..7

    #pragma unroll
    for (int i = 0; i < 4; ++i) {
        const int k = tk * 32 + ty + i * 8;
        const int h = th * 32 + tx;
        tile[ty + i * 8][tx] = (h < dd.H)
            ? dd.src[((size_t)e * dd.K + k) * dd.H + h] : 0.0f;
    }
    __syncthreads();
    #pragma unroll
    for (int i = 0; i < 4; ++i) {
        const int h = th * 32 + ty + i * 8;
        const int k = tk * 32 + tx;
        if (h < dd.H)
            dst[dd.dstOff + ((size_t)e * dd.H + h) * dd.K + k] = f2bf(tile[tx][ty + i * 8]);
    }
}

// Flat fp32 gather-pack (biases + score L3 weights)
struct CDesc { const float* src; u32 dstOff; u32 n; };
struct CTable { CDesc d[14]; };

__global__ __launch_bounds__(256)
void pack_f32(CTable t, float* __restrict__ dst)
{
    const CDesc dd = t.d[blockIdx.y];
    const u32 i = blockIdx.x * 256 + threadIdx.x;
    if (i < dd.n) dst[dd.dstOff + i] = dd.src[i];
}

// ---------------------------------------------------------------------------
extern "C" void kernel_launch(void* const* d_in, const int* in_sizes, int n_in,
                              void* d_out, int out_size, void* d_ws, size_t ws_size,
                              hipStream_t stream)
{
    (void)in_sizes; (void)n_in; (void)out_size; (void)ws_size;

    const float* x   = (const float*)d_in[0];
    const float* rw1 = (const float*)d_in[1];
    const float* rb1 = (const float*)d_in[2];
    const float* rw2 = (const float*)d_in[3];
    const float* rb2 = (const float*)d_in[4];
    const float* rw3 = (const float*)d_in[5];
    const float* rb3 = (const float*)d_in[6];

    float* out = (float*)d_out;
    char* ws = (char*)d_ws;

    // ---- workspace layout ----
    u16*   xb      = (u16*)(ws);                   // [N,128] bf16   12,582,912 B
    u16*   wtb     = (u16*)(ws + 12582912);        // packed bf16 W   1,843,200 B
    float* biasp   = (float*)(ws + 14426112);      // packed fp32        21,504 B
    float* part    = (float*)(ws + 14447616);      // [192,5]
    float* tp      = (float*)(ws + 14451712);      // [N,2]
    int*   ti      = (int*)  (ws + 14844928);      // [N,2]
    float* shscore = (float*)(ws + 15238144);      // [N] fp32          196,608 B
    float* shtraj  = (float*)(ws + 15434752);      // [N,120] fp32   23,592,960 B
    float* rh1     = (float*)(ws + 39027712);      // [N,256] fp32   50,331,648 B
    float* rh2     = (float*)(ws + 89359360);      // [N,128] fp32   25,165,824 B

    const dim3 blk(256);

    // ---- router (fp32: topk_idx must match reference ordering exactly) ----
    mlp_gemm<true ><<<dim3(N_TOK / 128, 2), blk, 0, stream>>>(x,   rw1, rb1, rh1, 128, 256);
    mlp_gemm<true ><<<dim3(N_TOK / 128, 1), blk, 0, stream>>>(rh1, rw2, rb2, rh2, 256, 128);
    router_l3post<<<dim3(N_TOK / 256), blk, 0, stream>>>(
        rh2, rw3, rb3, out + OFF_LOGITS, out + OFF_IDX, tp, ti, part);
    aux_kernel<<<dim3(1), blk, 0, stream>>>(part, out + OFF_AUX);

    // ---- conversions / packing ----
    convert_x<<<dim3(N_TOK * 128 / 1024), blk, 0, stream>>>(x, xb);
    {
        WTable t;
        t.d[0] = { (const float*)d_in[19], O_T1,              128, 256, 5 };
        t.d[1] = { (const float*)d_in[7],  O_T1 + 5 * 32768,  128, 256, 1 };
        t.d[2] = { (const float*)d_in[21], O_T2,              256, 256, 5 };
        t.d[3] = { (const float*)d_in[9],  O_T2 + 5 * 65536,  256, 256, 1 };
        t.d[4] = { (const float*)d_in[23], O_T3,              256, 120, 5 };
        t.d[5] = { (const float*)d_in[11], O_T3 + 5 * 30720,  256, 120, 1 };
        t.d[6] = { (const float*)d_in[25], O_S1,              128, 128, 5 };
        t.d[7] = { (const float*)d_in[13], O_S1 + 5 * 16384,  128, 128, 1 };
        t.d[8] = { (const float*)d_in[27], O_S2,              128,  64, 5 };
        t.d[9] = { (const float*)d_in[15], O_S2 + 5 * 8192,   128,  64, 1 };
        convert_w<<<dim3(320, 10), blk, 0, stream>>>(t, wtb);
    }
    {
        CTable t;
        t.d[0]  = { (const float*)d_in[20], OB_T1,        1280 };
        t.d[1]  = { (const float*)d_in[8],  OB_T1 + 1280,  256 };
        t.d[2]  = { (const float*)d_in[22], OB_T2,        1280 };
        t.d[3]  = { (const float*)d_in[10], OB_T2 + 1280,  256 };
        t.d[4]  = { (const float*)d_in[24], OB_T3,         600 };
        t.d[5]  = { (const float*)d_in[12], OB_T3 + 600,   120 };
        t.d[6]  = { (const float*)d_in[26], OB_S1,         640 };
        t.d[7]  = { (const float*)d_in[14], OB_S1 + 640,   128 };
        t.d[8]  = { (const float*)d_in[28], OB_S2,         320 };
        t.d[9]  = { (const float*)d_in[16], OB_S2 + 320,    64 };
        t.d[10] = { (const float*)d_in[29], OW_S3,         320 };
        t.d[11] = { (const float*)d_in[17], OW_S3 + 320,    64 };
        t.d[12] = { (const float*)d_in[30], OB_S3,           5 };
        t.d[13] = { (const float*)d_in[18], OB_S3 + 5,       1 };
        pack_f32<<<dim3(5, 14), blk, 0, stream>>>(t, biasp);
    }

    // ---- fully fused expert path (blockIdx.y = expert, 5 unshared + shared) ----
    expert_fused<<<dim3(N_TOK / 64, 6), dim3(512), 0, stream>>>(
        xb, wtb, biasp, out, shtraj, shscore);

    // ---- final combine (traj + score) ----
    combine_all<<<dim3(N_TOK * 30 / 256), blk, 0, stream>>>(
        out + OFF_TRAJALL, shtraj, out + OFF_SCOREALL, shscore,
        tp, ti, out + OFF_TRAJ, out + OFF_SCORE);
}

// Round 17
// 365.401 us; speedup vs baseline: 1.1394x; 1.0671x over previous
//
#include <hip/hip_runtime.h>
#include <hip/hip_bf16.h>
#include <cstdint>
#include <cstddef>

// Problem constants
static constexpr int N_TOK = 49152;     // B*M = 8192*6
// d_out offsets (floats), outputs concatenated in reference return order
static constexpr size_t OFF_TRAJ     = 0;          // [N,120]
static constexpr size_t OFF_SCORE    = 5898240;    // [N]
static constexpr size_t OFF_LOGITS   = 5947392;    // [N,5]
static constexpr size_t OFF_IDX      = 6193152;    // [N,2]  (ints stored as floats)
static constexpr size_t OFF_AUX      = 6291456;    // [1]
static constexpr size_t OFF_TRAJALL  = 6291457;    // [5,N,120]
static constexpr size_t OFF_SCOREALL = 35782657;   // [5,N]

typedef short s16x8 __attribute__((ext_vector_type(8)));
typedef float f32x4 __attribute__((ext_vector_type(4)));
typedef f32x4 f32x4u __attribute__((aligned(4)));   // reduced-alignment variant
typedef unsigned int u32;
typedef unsigned short u16;

// packed bf16 weight offsets (u16 elems): [6][H][K] per layer (experts 0-4, shared=5)
static constexpr u32 O_T1 = 0,      O_T2 = 196608, O_T3 = 589824;
static constexpr u32 O_S1 = 774144, O_S2 = 872448;
// packed fp32 offsets (floats)
static constexpr u32 OB_T1 = 0, OB_T2 = 1536, OB_T3 = 3072, OB_S1 = 3792, OB_S2 = 4560;
static constexpr u32 OW_S3 = 4944, OB_S3 = 5328;

// exact gelu (router path: logits feed exact-match topk)
__device__ __forceinline__ float gelu_exact(float x) {
    return 0.5f * x * (1.0f + erff(x * 0.70710678118654752440f));
}
// fast gelu: x*sigmoid(1.5957691*(x+0.044715x^3)); rcp instead of exact division
__device__ __forceinline__ float gelu_f(float x) {
    const float x2 = x * x;
    const float u  = x * fmaf(0.07135486172f, x2, 1.5957691216057308f);
    const float t  = __expf(-u);
    return x * __builtin_amdgcn_rcpf(1.0f + t);
}
__device__ __forceinline__ float bf2f(u16 u) {
    return __uint_as_float(((u32)u) << 16);
}
__device__ __forceinline__ u16 f2bf(float v) {
    return ((__hip_bfloat16_raw)__float2bfloat16(v)).x;
}
__device__ __forceinline__ void gload16(const u16* g, u16* l) {
    __builtin_amdgcn_global_load_lds(
        (const __attribute__((address_space(1))) u32*)g,
        (__attribute__((address_space(3))) u32*)l, 16, 0, 0);
}
#define MFMA16(a, b, c) __builtin_amdgcn_mfma_f32_16x16x32_bf16(a, b, c, 0, 0, 0)
#define SBAR() __builtin_amdgcn_sched_barrier(0)

// swizzled LDS fragment read: logical (row r, 16B-chunk c) at slot c^(r&mask)
__device__ __forceinline__ s16x8 lds_frag(const u16* buf, int RBu16, int r, int c, int mask) {
    return *(const s16x8*)&buf[r * RBu16 + ((c ^ (r & mask)) << 3)];
}
// swizzled 8B LDS store of 4 consecutive bf16 cols (colb % 4 == 0)
__device__ __forceinline__ void lds_store4(u16* buf, int RBu16, int r, int colb, int mask,
                                           float v0, float v1, float v2, float v3) {
    const int ch = (colb >> 3) ^ (r & mask);
    ushort4 st = { f2bf(v0), f2bf(v1), f2bf(v2), f2bf(v3) };
    *(ushort4*)&buf[r * RBu16 + ch * 8 + (colb & 7)] = st;
}

// ---------------------------------------------------------------------------
// MEGA KERNEL: blockIdx.y 0..5 = fused expert path (64 tokens, bf16 MFMA);
// blockIdx.y 6..7 = fp32 router path (32 tokens). Router blocks co-schedule
// with expert blocks, so their barrier/staging stalls are backfilled — the
// serial ~115us router chain folds into the latency-bound expert kernel.
// LDS 48 KB shared: xs 16 KB + hb 32 KB, both time-shared per path.
// ---------------------------------------------------------------------------
__global__ __launch_bounds__(512, 2)
void mega_fused(const u16* __restrict__ xb, const u16* __restrict__ wtb,
                const float* __restrict__ biasp, float* __restrict__ out,
                float* __restrict__ shtraj, float* __restrict__ shscore,
                const float* __restrict__ x, const float* __restrict__ rw1,
                const float* __restrict__ rb1, const float* __restrict__ rw2,
                const float* __restrict__ rb2, const float* __restrict__ rw3,
                const float* __restrict__ rb3, float* __restrict__ logits,
                float* __restrict__ oidx, float* __restrict__ tp,
                int* __restrict__ ti, float* __restrict__ part)
{
    __shared__ u16 xs[64 * 128];   // 16 KB
    __shared__ u16 hb[64 * 256];   // 32 KB
    float* hbf = (float*)hb;
    u16* s1p = hb;
    u16* s2p = hb + 64 * 128;

    const int tid = threadIdx.x;
    const int ey  = blockIdx.y;

    if (ey >= 6) {
        // ================= ROUTER PATH (fp32, 32 tokens/block) =============
        float* fA = (float*)xs;    // 16 KB: x [32][128] -> w2 chunk -> h2
        float* fB = hbf;           // 32 KB: w1 chunks -> h1 [32][256] -> probs
        const int blk = (ey - 6) * 768 + blockIdx.x;     // 0..1535
        const int r0  = blk * 32;
        const int tg  = tid >> 6;          // 0..7 -> tokens tg*4..+3
        const int cl  = tid & 63;
        const int t0  = tg * 4;

        // load x tile [32][128] fp32
        {
            const float* src = x + (size_t)r0 * 128;
            #pragma unroll
            for (int i = 0; i < 2; ++i)
                *(f32x4*)&fA[i * 2048 + tid * 4] = *(const f32x4*)&src[i * 2048 + tid * 4];
        }
        __syncthreads();

        // ---- L1: h1 = gelu(x @ rw1 + rb1), K=128 in 4 chunks (staged in fB)
        float acc1[4][4] = {};
        for (int k0 = 0; k0 < 128; k0 += 32) {
            __syncthreads();
            #pragma unroll
            for (int i = 0; i < 4; ++i)
                *(f32x4*)&fB[i * 2048 + tid * 4] =
                    *(const f32x4*)&rw1[(size_t)k0 * 256 + i * 2048 + tid * 4];
            __syncthreads();
            #pragma unroll
            for (int kk = 0; kk < 32; ++kk) {
                const f32x4 wv = *(const f32x4*)&fB[kk * 256 + cl * 4];
                #pragma unroll
                for (int i = 0; i < 4; ++i) {
                    const float xv = fA[(t0 + i) * 128 + k0 + kk];
                    acc1[i][0] = fmaf(xv, wv[0], acc1[i][0]);
                    acc1[i][1] = fmaf(xv, wv[1], acc1[i][1]);
                    acc1[i][2] = fmaf(xv, wv[2], acc1[i][2]);
                    acc1[i][3] = fmaf(xv, wv[3], acc1[i][3]);
                }
            }
        }
        __syncthreads();   // last chunk reads done -> fB reusable for h1
        {
            const f32x4 b1 = *(const f32x4*)&rb1[cl * 4];
            #pragma unroll
            for (int i = 0; i < 4; ++i) {
                fB[(t0 + i) * 256 + cl * 4 + 0] = gelu_exact(acc1[i][0] + b1[0]);
                fB[(t0 + i) * 256 + cl * 4 + 1] = gelu_exact(acc1[i][1] + b1[1]);
                fB[(t0 + i) * 256 + cl * 4 + 2] = gelu_exact(acc1[i][2] + b1[2]);
                fB[(t0 + i) * 256 + cl * 4 + 3] = gelu_exact(acc1[i][3] + b1[3]);
            }
        }
        __syncthreads();   // h1 visible; x reads long done -> fA reusable

        // ---- L2: h2 = gelu(h1 @ rw2 + rb2), K=256 in 8 chunks (staged in fA)
        float acc2[4][2] = {};
        for (int k0 = 0; k0 < 256; k0 += 32) {
            __syncthreads();
            #pragma unroll
            for (int i = 0; i < 2; ++i)
                *(f32x4*)&fA[i * 2048 + tid * 4] =
                    *(const f32x4*)&rw2[(size_t)k0 * 128 + i * 2048 + tid * 4];
            __syncthreads();
            #pragma unroll
            for (int kk = 0; kk < 32; ++kk) {
                const float2 wv = *(const float2*)&fA[kk * 128 + cl * 2];
                #pragma unroll
                for (int i = 0; i < 4; ++i) {
                    const float hv = fB[(t0 + i) * 256 + k0 + kk];
                    acc2[i][0] = fmaf(hv, wv.x, acc2[i][0]);
                    acc2[i][1] = fmaf(hv, wv.y, acc2[i][1]);
                }
            }
        }
        __syncthreads();   // last chunk reads done -> fA reusable for h2
        {
            const float2 b2 = *(const float2*)&rb2[cl * 2];
            #pragma unroll
            for (int i = 0; i < 4; ++i) {
                fA[(t0 + i) * 128 + cl * 2 + 0] = gelu_exact(acc2[i][0] + b2.x);
                fA[(t0 + i) * 128 + cl * 2 + 1] = gelu_exact(acc2[i][1] + b2.y);
            }
        }
        __syncthreads();   // h2 ready; h1 reads done -> fB reusable for probs

        // ---- L3 + softmax + top-2 (token = tid>>4, 16 lanes K-split) ----
        {
            const int tok = tid >> 4;
            const int ln  = tid & 15;
            float l5[5] = {0.f, 0.f, 0.f, 0.f, 0.f};
            #pragma unroll
            for (int kk = 0; kk < 8; ++kk) {
                const float hv = fA[tok * 128 + ln * 8 + kk];
                #pragma unroll
                for (int e = 0; e < 5; ++e)
                    l5[e] = fmaf(hv, rw3[(size_t)(ln * 8 + kk) * 5 + e], l5[e]);
            }
            #pragma unroll
            for (int off = 8; off > 0; off >>= 1)
                #pragma unroll
                for (int e = 0; e < 5; ++e)
                    l5[e] += __shfl_xor(l5[e], off);

            if (ln == 0) {
                const int n = r0 + tok;
                float l[5];
                #pragma unroll
                for (int e = 0; e < 5; ++e) {
                    l[e] = l5[e] + rb3[e];
                    logits[(size_t)n * 5 + e] = l[e];
                }
                float m = l[0];
                #pragma unroll
                for (int e = 1; e < 5; ++e) m = fmaxf(m, l[e]);
                float p[5], s = 0.f;
                #pragma unroll
                for (int e = 0; e < 5; ++e) { p[e] = expf(l[e] - m); s += p[e]; }
                const float inv = 1.0f / s;
                #pragma unroll
                for (int e = 0; e < 5; ++e) fB[tok * 5 + e] = p[e] * inv;

                // top-2 (ties keep lower index, matching jax.lax.top_k)
                int i0 = 0; float v0 = l[0];
                #pragma unroll
                for (int e = 1; e < 5; ++e) if (l[e] > v0) { v0 = l[e]; i0 = e; }
                int i1 = -1; float v1 = -1e30f;
                #pragma unroll
                for (int e = 0; e < 5; ++e) if (e != i0 && l[e] > v1) { v1 = l[e]; i1 = e; }

                const float t  = expf(v1 - v0);
                const float q0 = 1.0f / (1.0f + t);
                const float q1 = t / (1.0f + t);

                oidx[(size_t)n * 2]     = (float)i0;
                oidx[(size_t)n * 2 + 1] = (float)i1;
                tp[n * 2] = q0; tp[n * 2 + 1] = q1;
                ti[n * 2] = i0; ti[n * 2 + 1] = i1;
            }
        }
        __syncthreads();
        if (tid < 5) {
            float s = 0.f;
            #pragma unroll 8
            for (int t = 0; t < 32; ++t) s += fB[t * 5 + tid];
            part[blk * 5 + tid] = s;
        }
        return;
    }

    // ================= EXPERT PATH (bf16 MFMA, 64 tokens/block) ============
    const int lane = tid & 63;
    const int wave = tid >> 6;          // 0..7
    const int row0 = blockIdx.x * 64;
    const int e    = ey;                // expert 0..5 (5 = shared)
    const int frow = lane & 15;
    const int kgrp = lane >> 4;         // 0..3
    const int c0   = wave * 32;         // L1/L2 col slice

    // stage x tile (linear LDS dest, inverse-swizzled global source, mask 15)
    #pragma unroll
    for (int i = 0; i < 2; ++i) {
        const int idx = i * 512 + tid;
        const int r = idx >> 4, c = idx & 15;
        gload16(xb + (size_t)(row0 + r) * 128 + ((c ^ (r & 15)) << 3), &xs[idx * 8]);
    }

    const int col3 = wave * 16 + kgrp * 4;                       // L3 output colbase
    const int r3   = (wave * 16 + frow) < 120 ? (wave * 16 + frow) : 119;

    // prefetch L1 weight fragments
    s16x8 wf1[4][2];
    {
        const u16* w1p = wtb + O_T1 + e * 32768;
        #pragma unroll
        for (int n = 0; n < 2; ++n) {
            const u16* p = w1p + (size_t)(c0 + n * 16 + frow) * 128 + kgrp * 8;
            #pragma unroll
            for (int ks = 0; ks < 4; ++ks) wf1[ks][n] = *(const s16x8*)(p + ks * 32);
        }
    }
    SBAR();

    __syncthreads();   // B0: xs ready (drains vmcnt)

    // ---------- L1: xs[64,128] -> h1 (into hb) ----------
    f32x4 acc1[4][2] = {};
    #pragma unroll
    for (int ks = 0; ks < 4; ++ks)
        #pragma unroll
        for (int m = 0; m < 4; ++m) {
            const s16x8 a = lds_frag(xs, 128, m * 16 + frow, ks * 4 + kgrp, 15);
            #pragma unroll
            for (int n = 0; n < 2; ++n)
                acc1[m][n] = MFMA16(wf1[ks][n], a, acc1[m][n]);
        }

    // issue L2 first-half weight + L1 bias prefetch, pinned before stores
    const u16* w2p = wtb + O_T2 + e * 65536;
    s16x8 wf2a[4][2];
    f32x4 bb1[2];
    #pragma unroll
    for (int n = 0; n < 2; ++n) {
        const u16* p = w2p + (size_t)(c0 + n * 16 + frow) * 256 + kgrp * 8;
        #pragma unroll
        for (int ks = 0; ks < 4; ++ks) wf2a[ks][n] = *(const s16x8*)(p + ks * 32);
        bb1[n] = *(const f32x4*)&biasp[OB_T1 + e * 256 + c0 + n * 16 + kgrp * 4];
    }
    SBAR();

    {   // store h1 (+bias+gelu) -> hb
        #pragma unroll
        for (int n = 0; n < 2; ++n) {
            const int colb = c0 + n * 16 + kgrp * 4;
            #pragma unroll
            for (int m = 0; m < 4; ++m)
                lds_store4(hb, 256, m * 16 + frow, colb, 15,
                           gelu_f(acc1[m][n][0] + bb1[n][0]),
                           gelu_f(acc1[m][n][1] + bb1[n][1]),
                           gelu_f(acc1[m][n][2] + bb1[n][2]),
                           gelu_f(acc1[m][n][3] + bb1[n][3]));
        }
    }
    __syncthreads();   // B1: h1 ready

    // issue L2 second-half weight prefetch
    s16x8 wf2b[4][2];
    #pragma unroll
    for (int n = 0; n < 2; ++n) {
        const u16* p = w2p + (size_t)(c0 + n * 16 + frow) * 256 + 128 + kgrp * 8;
        #pragma unroll
        for (int ks = 0; ks < 4; ++ks) wf2b[ks][n] = *(const s16x8*)(p + ks * 32);
    }
    SBAR();

    // ---------- L2: hb(h1) -> acc2 regs, K=256 ----------
    f32x4 acc2[4][2] = {};
    #pragma unroll
    for (int ks = 0; ks < 4; ++ks)
        #pragma unroll
        for (int m = 0; m < 4; ++m) {
            const s16x8 a = lds_frag(hb, 256, m * 16 + frow, ks * 4 + kgrp, 15);
            #pragma unroll
            for (int n = 0; n < 2; ++n)
                acc2[m][n] = MFMA16(wf2a[ks][n], a, acc2[m][n]);
        }
    #pragma unroll
    for (int ks = 0; ks < 4; ++ks)
        #pragma unroll
        for (int m = 0; m < 4; ++m) {
            const s16x8 a = lds_frag(hb, 256, m * 16 + frow, (ks + 4) * 4 + kgrp, 15);
            #pragma unroll
            for (int n = 0; n < 2; ++n)
                acc2[m][n] = MFMA16(wf2b[ks][n], a, acc2[m][n]);
        }

    // issue L3 weight + L2 bias prefetch
    s16x8 wf3[8];
    f32x4 bb2[2];
    {
        const u16* w3p = wtb + O_T3 + e * 30720 + (size_t)r3 * 256 + kgrp * 8;
        #pragma unroll
        for (int ks = 0; ks < 8; ++ks) wf3[ks] = *(const s16x8*)(w3p + ks * 32);
        #pragma unroll
        for (int n = 0; n < 2; ++n)
            bb2[n] = *(const f32x4*)&biasp[OB_T2 + e * 256 + c0 + n * 16 + kgrp * 4];
    }
    SBAR();
    __syncthreads();   // B2: all h1 reads done -> hb reusable

    {   // store h2 (+bias+gelu) -> hb
        #pragma unroll
        for (int n = 0; n < 2; ++n) {
            const int colb = c0 + n * 16 + kgrp * 4;
            #pragma unroll
            for (int m = 0; m < 4; ++m)
                lds_store4(hb, 256, m * 16 + frow, colb, 15,
                           gelu_f(acc2[m][n][0] + bb2[n][0]),
                           gelu_f(acc2[m][n][1] + bb2[n][1]),
                           gelu_f(acc2[m][n][2] + bb2[n][2]),
                           gelu_f(acc2[m][n][3] + bb2[n][3]));
        }
    }
    __syncthreads();   // B3: h2 ready

    // issue S1 weight + L3 bias prefetch (complete under L3 MFMAs)
    s16x8 wfs1[4];
    f32x4 bb3 = *(const f32x4u*)&biasp[OB_T3 + e * 120 + (col3 < 120 ? col3 : 116)];
    {
        const u16* p = wtb + O_S1 + e * 16384 + (size_t)(wave * 16 + frow) * 128 + kgrp * 8;
        #pragma unroll
        for (int ks = 0; ks < 4; ++ks) wfs1[ks] = *(const s16x8*)(p + ks * 32);
    }
    SBAR();

    // ---------- L3: hb(h2) -> acc3 regs (held through the score phase) ----------
    f32x4 acc3[4] = {};
    #pragma unroll
    for (int ks = 0; ks < 8; ++ks)
        #pragma unroll
        for (int m = 0; m < 4; ++m) {
            const s16x8 a = lds_frag(hb, 256, m * 16 + frow, ks * 4 + kgrp, 15);
            acc3[m] = MFMA16(wf3[ks], a, acc3[m]);
        }
    __syncthreads();   // B4: all h2 reads done -> hb reusable for s1/s2

    // ---------- S1: xs -> s1 (hb[0:16K]) ----------
    f32x4 accs1[4] = {};
    #pragma unroll
    for (int ks = 0; ks < 4; ++ks)
        #pragma unroll
        for (int m = 0; m < 4; ++m) {
            const s16x8 a = lds_frag(xs, 128, m * 16 + frow, ks * 4 + kgrp, 15);
            accs1[m] = MFMA16(wfs1[ks], a, accs1[m]);
        }
    // issue S2 weight + S1 bias prefetch
    s16x8 wfs2[4];
    f32x4 bbs1;
    {
        const u16* p = wtb + O_S2 + e * 8192 + (size_t)((wave & 3) * 16 + frow) * 128 + kgrp * 8;
        #pragma unroll
        for (int ks = 0; ks < 4; ++ks) wfs2[ks] = *(const s16x8*)(p + ks * 32);
        bbs1 = *(const f32x4*)&biasp[OB_S1 + e * 128 + wave * 16 + kgrp * 4];
    }
    SBAR();
    {
        const int colb = wave * 16 + kgrp * 4;
        #pragma unroll
        for (int m = 0; m < 4; ++m)
            lds_store4(s1p, 128, m * 16 + frow, colb, 15,
                       gelu_f(accs1[m][0] + bbs1[0]),
                       gelu_f(accs1[m][1] + bbs1[1]),
                       gelu_f(accs1[m][2] + bbs1[2]),
                       gelu_f(accs1[m][3] + bbs1[3]));
    }
    __syncthreads();   // B5: s1 ready

    // ---------- S2: s1 -> s2 (hb[16K:24K]) (waves 0-3) ----------
    if (wave < 4) {
        f32x4 accs2[4] = {};
        #pragma unroll
        for (int ks = 0; ks < 4; ++ks)
            #pragma unroll
            for (int m = 0; m < 4; ++m) {
                const s16x8 a = lds_frag(s1p, 128, m * 16 + frow, ks * 4 + kgrp, 15);
                accs2[m] = MFMA16(wfs2[ks], a, accs2[m]);
            }
        const int colb = wave * 16 + kgrp * 4;
        const f32x4 bb = *(const f32x4*)&biasp[OB_S2 + e * 64 + colb];
        #pragma unroll
        for (int m = 0; m < 4; ++m)
            lds_store4(s2p, 64, m * 16 + frow, colb, 7,
                       gelu_f(accs2[m][0] + bb[0]),
                       gelu_f(accs2[m][1] + bb[1]),
                       gelu_f(accs2[m][2] + bb[2]),
                       gelu_f(accs2[m][3] + bb[3]));
    }
    __syncthreads();   // B6: s2 ready

    // ---------- S3: dot64 per token (512 thr = 64 tok x 8 kc) ----------
    {
        const int tok = tid >> 3;          // 0..63
        const int kc  = tid & 7;           // 0..7
        const float* w3s = biasp + OW_S3 + e * 64 + kc * 8;
        const s16x8 v = lds_frag(s2p, 64, tok, kc, 7);
        float p = 0.f;
        #pragma unroll
        for (int j = 0; j < 8; ++j) p = fmaf(bf2f((u16)v[j]), w3s[j], p);
        p += __shfl_xor(p, 1);
        p += __shfl_xor(p, 2);
        p += __shfl_xor(p, 4);
        if (kc == 0) {
            const float val = p + biasp[OB_S3 + e];
            if (e < 5) out[OFF_SCOREALL + (size_t)e * N_TOK + row0 + tok] = val;
            else       shscore[row0 + tok] = val;
        }
    }
    __syncthreads();   // B7: s2 reads done -> hb reusable for f32 staging

    // ---------- stage traj f32 tile [64][124] (padded) ----------
    if (col3 < 120) {
        #pragma unroll
        for (int m = 0; m < 4; ++m) {
            f32x4 v;
            #pragma unroll
            for (int j = 0; j < 4; ++j) v[j] = acc3[m][j] + bb3[j];
            *(f32x4*)&hbf[(m * 16 + frow) * 124 + col3] = v;
        }
    }
    __syncthreads();   // B8: staging complete

    // ---- 16B-ALIGNED PLAIN contiguous copy of 7680 floats ----
    {
        float* dst = (e < 5) ? out + OFF_TRAJALL + ((size_t)e * N_TOK + row0) * 120
                             : shtraj + (size_t)row0 * 120;
        const int head = (int)((16 - (((size_t)dst) & 15)) & 15) >> 2;  // 0..3 floats
        const int nvec = (7680 - head) >> 2;
        const int tail = 7680 - head - (nvec << 2);
        if (tid < head) {
            const int t0i = tid;
            dst[t0i] = hbf[(t0i / 120) * 124 + (t0i % 120)];
        }
        if (tid >= 8 && tid < 8 + tail) {
            const int t0i = 7680 - tail + (tid - 8);
            dst[t0i] = hbf[(t0i / 120) * 124 + (t0i % 120)];
        }
        #pragma unroll
        for (int i = 0; i < 4; ++i) {
            const int v = i * 512 + tid;
            if (v < nvec) {
                const int q = head + v * 4;
                f32x4 val;
                #pragma unroll
                for (int j = 0; j < 4; ++j) {
                    const int qq = q + j;
                    const int tk = qq / 120;
                    val[j] = hbf[tk * 124 + (qq - tk * 120)];
                }
                *(f32x4*)(dst + q) = val;     // aligned plain store
            }
        }
    }
}

__global__ __launch_bounds__(256)
void aux_kernel(const float* __restrict__ part, float* __restrict__ aux)
{
    __shared__ float avg[5];
    const int tid = threadIdx.x;
    if (tid < 5) {
        float s = 0.f;
        for (int b = 0; b < 1536; ++b) s += part[b * 5 + tid];
        avg[tid] = s / (float)N_TOK;
    }
    __syncthreads();
    if (tid == 0) {
        float ent = 0.f, l2 = 0.f;
        #pragma unroll
        for (int e = 0; e < 5; ++e) {
            ent -= avg[e] * logf(avg[e] + 1e-8f);
            float d = avg[e] - 0.2f;
            l2 += d * d;
        }
        l2 *= (1.0f / 5.0f);
        aux[0] = -ent * 0.01f + 0.01f * l2;
    }
}

// ---------------------------------------------------------------------------
// Final combine: traj = 0.3*shared + 0.7*(p0*traj[i0]+p1*traj[i1]); also score.
// ---------------------------------------------------------------------------
__global__ __launch_bounds__(256)
void combine_all(const float* __restrict__ trajall, const float* __restrict__ shtraj,
                 const float* __restrict__ scoreall, const float* __restrict__ shscore,
                 const float* __restrict__ tp, const int* __restrict__ ti,
                 float* __restrict__ ftraj, float* __restrict__ fscore)
{
    const int i4 = blockIdx.x * 256 + threadIdx.x;   // < N*30
    const int n  = i4 / 30;
    const int q4 = (i4 - n * 30) * 4;
    const int i0 = ti[n * 2], i1 = ti[n * 2 + 1];
    const float p0 = tp[n * 2], p1 = tp[n * 2 + 1];

    const f32x4 a = *(const f32x4u*)&trajall[((size_t)i0 * N_TOK + n) * 120 + q4];
    const f32x4 b = *(const f32x4u*)&trajall[((size_t)i1 * N_TOK + n) * 120 + q4];
    const f32x4 s = *(const f32x4*)&shtraj[(size_t)n * 120 + q4];
    f32x4 r;
    #pragma unroll
    for (int j = 0; j < 4; ++j)
        r[j] = 0.3f * s[j] + 0.7f * (p0 * a[j] + p1 * b[j]);
    *(f32x4*)&ftraj[(size_t)n * 120 + q4] = r;

    if (q4 == 0) {
        const float sa = scoreall[(size_t)i0 * N_TOK + n];
        const float sb = scoreall[(size_t)i1 * N_TOK + n];
        fscore[n] = 0.3f * shscore[n] + 0.7f * (p0 * sa + p1 * sb);
    }
}

// ---------------------------------------------------------------------------
__global__ __launch_bounds__(256)
void convert_x(const float* __restrict__ x, u16* __restrict__ xb)
{
    const size_t i = ((size_t)blockIdx.x * 256 + threadIdx.x) * 4;
    float4 v = *(const float4*)(x + i);
    ushort4 o;
    o.x = f2bf(v.x); o.y = f2bf(v.y); o.z = f2bf(v.z); o.w = f2bf(v.w);
    *(ushort4*)(xb + i) = o;
}

// Weight convert+transpose via LDS tiles (coalesced both sides):
// src fp32 [nz][K][H] -> dst bf16 [nz][H][K]
struct WDesc { const float* src; u32 dstOff; int K, H, nz; };
struct WTable { WDesc d[10]; };

__global__ __launch_bounds__(256)
void convert_w(WTable t, u16* __restrict__ dst)
{
    const WDesc dd = t.d[blockIdx.y];
    const int tilesK = dd.K >> 5;
    const int tilesH = (dd.H + 31) >> 5;
    const int tt = blockIdx.x;
    if (tt >= tilesK * tilesH * dd.nz) return;
    const int e  = tt / (tilesK * tilesH);
    const int r  = tt - e * (tilesK * tilesH);
    const int th = r / tilesK;
    const int tk = r - th * tilesK;

    __shared__ float tile[32][33];
    const int tx = threadIdx.x & 31;
    const int ty = threadIdx.x >> 5;     // 0..7

    #pragma unroll
    for (int i = 0; i < 4; ++i) {
        const int k = tk * 32 + ty + i * 8;
        const int h = th * 32 + tx;
        tile[ty + i * 8][tx] = (h < dd.H)
            ? dd.src[((size_t)e * dd.K + k) * dd.H + h] : 0.0f;
    }
    __syncthreads();
    #pragma unroll
    for (int i = 0; i < 4; ++i) {
        const int h = th * 32 + ty + i * 8;
        const int k = tk * 32 + tx;
        if (h < dd.H)
            dst[dd.dstOff + ((size_t)e * dd.H + h) * dd.K + k] = f2bf(tile[tx][ty + i * 8]);
    }
}

// Flat fp32 gather-pack (biases + score L3 weights)
struct CDesc { const float* src; u32 dstOff; u32 n; };
struct CTable { CDesc d[14]; };

__global__ __launch_bounds__(256)
void pack_f32(CTable t, float* __restrict__ dst)
{
    const CDesc dd = t.d[blockIdx.y];
    const u32 i = blockIdx.x * 256 + threadIdx.x;
    if (i < dd.n) dst[dd.dstOff + i] = dd.src[i];
}

// ---------------------------------------------------------------------------
extern "C" void kernel_launch(void* const* d_in, const int* in_sizes, int n_in,
                              void* d_out, int out_size, void* d_ws, size_t ws_size,
                              hipStream_t stream)
{
    (void)in_sizes; (void)n_in; (void)out_size; (void)ws_size;

    const float* x   = (const float*)d_in[0];
    const float* rw1 = (const float*)d_in[1];
    const float* rb1 = (const float*)d_in[2];
    const float* rw2 = (const float*)d_in[3];
    const float* rb2 = (const float*)d_in[4];
    const float* rw3 = (const float*)d_in[5];
    const float* rb3 = (const float*)d_in[6];

    float* out = (float*)d_out;
    char* ws = (char*)d_ws;

    // ---- workspace layout ----
    u16*   xb      = (u16*)(ws);                   // [N,128] bf16   12,582,912 B
    u16*   wtb     = (u16*)(ws + 12582912);        // packed bf16 W   1,843,200 B
    float* biasp   = (float*)(ws + 14426112);      // packed fp32        21,504 B
    float* part    = (float*)(ws + 14447616);      // [1536,5]           30,720 B
    float* tp      = (float*)(ws + 14478336);      // [N,2]
    int*   ti      = (int*)  (ws + 14871552);      // [N,2]
    float* shscore = (float*)(ws + 15264768);      // [N] fp32          196,608 B
    float* shtraj  = (float*)(ws + 15461376);      // [N,120] fp32   23,592,960 B

    const dim3 blk(256);

    // ---- conversions / packing (expert-path inputs; independent of router) ----
    convert_x<<<dim3(N_TOK * 128 / 1024), blk, 0, stream>>>(x, xb);
    {
        WTable t;
        t.d[0] = { (const float*)d_in[19], O_T1,              128, 256, 5 };
        t.d[1] = { (const float*)d_in[7],  O_T1 + 5 * 32768,  128, 256, 1 };
        t.d[2] = { (const float*)d_in[21], O_T2,              256, 256, 5 };
        t.d[3] = { (const float*)d_in[9],  O_T2 + 5 * 65536,  256, 256, 1 };
        t.d[4] = { (const float*)d_in[23], O_T3,              256, 120, 5 };
        t.d[5] = { (const float*)d_in[11], O_T3 + 5 * 30720,  256, 120, 1 };
        t.d[6] = { (const float*)d_in[25], O_S1,              128, 128, 5 };
        t.d[7] = { (const float*)d_in[13], O_S1 + 5 * 16384,  128, 128, 1 };
        t.d[8] = { (const float*)d_in[27], O_S2,              128,  64, 5 };
        t.d[9] = { (const float*)d_in[15], O_S2 + 5 * 8192,   128,  64, 1 };
        convert_w<<<dim3(320, 10), blk, 0, stream>>>(t, wtb);
    }
    {
        CTable t;
        t.d[0]  = { (const float*)d_in[20], OB_T1,        1280 };
        t.d[1]  = { (const float*)d_in[8],  OB_T1 + 1280,  256 };
        t.d[2]  = { (const float*)d_in[22], OB_T2,        1280 };
        t.d[3]  = { (const float*)d_in[10], OB_T2 + 1280,  256 };
        t.d[4]  = { (const float*)d_in[24], OB_T3,         600 };
        t.d[5]  = { (const float*)d_in[12], OB_T3 + 600,   120 };
        t.d[6]  = { (const float*)d_in[26], OB_S1,         640 };
        t.d[7]  = { (const float*)d_in[14], OB_S1 + 640,   128 };
        t.d[8]  = { (const float*)d_in[28], OB_S2,         320 };
        t.d[9]  = { (const float*)d_in[16], OB_S2 + 320,    64 };
        t.d[10] = { (const float*)d_in[29], OW_S3,         320 };
        t.d[11] = { (const float*)d_in[17], OW_S3 + 320,    64 };
        t.d[12] = { (const float*)d_in[30], OB_S3,           5 };
        t.d[13] = { (const float*)d_in[18], OB_S3 + 5,       1 };
        pack_f32<<<dim3(5, 14), blk, 0, stream>>>(t, biasp);
    }

    // ---- MEGA kernel: experts (y=0..5) + router (y=6..7) co-scheduled ----
    mega_fused<<<dim3(N_TOK / 64, 8), dim3(512), 0, stream>>>(
        xb, wtb, biasp, out, shtraj, shscore,
        x, rw1, rb1, rw2, rb2, rw3, rb3,
        out + OFF_LOGITS, out + OFF_IDX, tp, ti, part);

    // ---- aux loss + final combine ----
    aux_kernel<<<dim3(1), blk, 0, stream>>>(part, out + OFF_AUX);
    combine_all<<<dim3(N_TOK * 30 / 256), blk, 0, stream>>>(
        out + OFF_TRAJALL, shtraj, out + OFF_SCOREALL, shscore,
        tp, ti, out + OFF_TRAJ, out + OFF_SCORE);
}